// Round 4
// baseline (753.598 us; speedup 1.0000x reference)
//
#include <hip/hip_runtime.h>
#include <hip/hip_bf16.h>

typedef __hip_bfloat16 bf16;
typedef unsigned int u32;

#define HHW 65536
#define SBH 580            // S row stride in bf16 (290 dwords; rows 4 apart -> banks +8 -> conflict-free)
#define SRU 290            // S row stride in u32

__device__ __forceinline__ float b2f(bf16 v) { return __bfloat162float(v); }
__device__ __forceinline__ bf16  f2b(float v) { return __float2bfloat16(v); }
__device__ __forceinline__ float blo(u32 p) { return __uint_as_float(p << 16); }
__device__ __forceinline__ float bhi(u32 p) { return __uint_as_float(p & 0xffff0000u); }

#define FMA8(A, s, wa, wb) \
  A[0] += (s)*wa.x; A[1] += (s)*wa.y; A[2] += (s)*wa.z; A[3] += (s)*wa.w; \
  A[4] += (s)*wb.x; A[5] += (s)*wb.y; A[6] += (s)*wb.z; A[7] += (s)*wb.w;

// ---------------- K0: transpose x (B,64,H,W) f32 -> xT (B,HW,64) bf16 ----------------
__global__ __launch_bounds__(256) void k_prep_x(const float* __restrict__ x, bf16* __restrict__ xT) {
    __shared__ bf16 tile[64][66];   // +2 pad: conflict-free transposed writes
    int g = blockIdx.x;             // 2048 blocks: b = g>>10, 64 pixels each
    int b = g >> 10;
    int pixbase = (g & 1023) << 6;
    int t = threadIdx.x;
    int pix = t & 63, ci0 = t >> 6;
    const float* xb = x + ((size_t)b * 64) * HHW + pixbase + pix;
    for (int ci = ci0; ci < 64; ci += 4)
        tile[pix][ci] = f2b(xb[(size_t)ci * HHW]);
    __syncthreads();
    bf16* dst = xT + ((size_t)b * HHW + pixbase) * 64;
    for (int i = t; i < 4096; i += 256)
        dst[i] = tile[i >> 6][i & 63];
}

// ---------------- K0b: weight/const prep ----------------
__global__ __launch_bounds__(256) void k_prep_w(
        const float* __restrict__ w_off, const float* __restrict__ w_def, const float* __restrict__ b_def,
        const float* __restrict__ bng, const float* __restrict__ bnb, const float* __restrict__ bnm, const float* __restrict__ bnv,
        const float* __restrict__ ds_w, const float* __restrict__ dsg, const float* __restrict__ dsb,
        const float* __restrict__ dsm, const float* __restrict__ dsv,
        float* __restrict__ wT, float* __restrict__ wloff, float* __restrict__ dws2,
        float* __restrict__ bnS, float* __restrict__ bnT2, float* __restrict__ dsT) {
    int tid = blockIdx.x * 256 + threadIdx.x;   // 32 blocks -> 8192 threads
    // wT[kci][co] = w_def[co][kci]   (kci = ci*9 + ky*3 + kx, 576 x 128)
    for (int i = tid; i < 576 * 128; i += 8192) {
        int kci = i >> 7, co = i & 127;
        wT[i] = w_def[co * 576 + kci];
    }
    // wloff[kci][20] = w_off[j][kci] padded with zeros (j<18)
    for (int i = tid; i < 576 * 20; i += 8192) {
        int kci = i / 20, j = i - kci * 20;
        wloff[i] = (j < 18) ? w_off[j * 576 + kci] : 0.f;
    }
    // dws2[co][ci] = ds_w * ds_bn_scale  (fold BN scale into 1x1 weights)
    if (tid < 8192) {
        int co = tid >> 6;
        float s2 = dsg[co] * rsqrtf(dsv[co] + 1e-5f);
        dws2[tid] = ds_w[tid] * s2;
    }
    if (tid < 128) {
        float s = bng[tid] * rsqrtf(bnv[tid] + 1e-5f);
        bnS[tid] = s;
        bnT2[tid] = (b_def[tid] - bnm[tid]) * s + bnb[tid];  // fold conv bias into BN shift
        float s2 = dsg[tid] * rsqrtf(dsv[tid] + 1e-5f);
        dsT[tid] = dsb[tid] - dsm[tid] * s2;
    }
}

// ---------------- K1: offset conv 3x3, 64 -> 18 (pad=1), f32 ----------------
__global__ __launch_bounds__(256) void k_off(const float* __restrict__ x,
        const float* __restrict__ wloff, const float* __restrict__ b_off,
        float* __restrict__ off) {
    int g = blockIdx.x;               // 512 blocks = b*256 + h
    int b = g >> 8, h = g & 255;
    int t = threadIdx.x;              // w
    float acc[20];
    #pragma unroll
    for (int j = 0; j < 20; ++j) acc[j] = 0.f;
    const float* xb = x + ((size_t)b * 64) * HHW;
    for (int ci = 0; ci < 64; ++ci) {
        const float* xc = xb + (size_t)ci * HHW;
        #pragma unroll
        for (int ky = 0; ky < 3; ++ky) {
            int y = h + ky - 1;
            if ((unsigned)y >= 256u) continue;
            const float* row = xc + y * 256;
            float v0 = (t >= 1)   ? row[t - 1] : 0.f;
            float v1 = row[t];
            float v2 = (t <= 254) ? row[t + 1] : 0.f;
            // wave-uniform global float4 reads (single fetch per wave, avoids LDS instr-rate bound)
            const float4* wr = (const float4*)(wloff + (ci * 9 + ky * 3) * 20);
            #pragma unroll
            for (int q = 0; q < 5; ++q) {
                float4 wv = wr[q];
                acc[q*4+0] += v0 * wv.x; acc[q*4+1] += v0 * wv.y;
                acc[q*4+2] += v0 * wv.z; acc[q*4+3] += v0 * wv.w;
            }
            #pragma unroll
            for (int q = 0; q < 5; ++q) {
                float4 wv = wr[5 + q];
                acc[q*4+0] += v1 * wv.x; acc[q*4+1] += v1 * wv.y;
                acc[q*4+2] += v1 * wv.z; acc[q*4+3] += v1 * wv.w;
            }
            #pragma unroll
            for (int q = 0; q < 5; ++q) {
                float4 wv = wr[10 + q];
                acc[q*4+0] += v2 * wv.x; acc[q*4+1] += v2 * wv.y;
                acc[q*4+2] += v2 * wv.z; acc[q*4+3] += v2 * wv.w;
            }
        }
    }
    float* ob = off + ((size_t)b * 18) * HHW + h * 256 + t;
    #pragma unroll
    for (int j = 0; j < 18; ++j) ob[(size_t)j * HHW] = acc[j] + b_off[j];
}

// ---------------- K2: deformable conv + BN + pooled partials ----------------
// block = 64 pixels (quarter row); S[64][576] bf16 in LDS; each thread: 8 co x 4 px
__global__ __launch_bounds__(256) void k_deform(const bf16* __restrict__ xT,
        const float* __restrict__ off, const float* __restrict__ wT,
        const float* __restrict__ bnS, const float* __restrict__ bnT2,
        bf16* __restrict__ out_pre, float* __restrict__ part) {
    __shared__ bf16 smem[64 * SBH];      // 74.2 KB -> 2 blocks/CU
    int blk = blockIdx.x;                // 2048 = 2 * 1024
    int b = blk >> 10;
    int tile = blk & 1023;
    int pixbase = tile << 6;             // 64 px, contiguous within one row
    int h = pixbase >> 8;
    int w0 = pixbase & 255;
    int t = threadIdx.x;

    // ---- phase 1: bilinear sampling into S[pix][ci*9+k] (bf16) ----
    {
        int ci = t & 63, pg = t >> 6;    // pg uniform per wave
        const bf16* xb = xT + ((size_t)b * HHW) * 64 + ci;
        const float* offb = off + ((size_t)b * 18) * HHW + pixbase;
        for (int it = 0; it < 144; ++it) {
            int pk = it * 4 + pg;        // (pix,k) pair, 0..575
            int pix = pk / 9;
            int k = pk - pix * 9;
            int ky = k / 3, kx = k - ky * 3;
            float dy = offb[(size_t)(2 * k) * HHW + pix];
            float dx = offb[(size_t)(2 * k + 1) * HHW + pix];
            float py = (float)(h + ky - 1) + dy;
            float px = (float)(w0 + pix + kx - 1) + dx;
            float fy = floorf(py), fx = floorf(px);
            int y0 = (int)fy, x0 = (int)fx;
            float wy1 = py - fy, wx1 = px - fx;
            float wy0 = 1.f - wy1, wx0 = 1.f - wx1;
            int y1 = y0 + 1, x1 = x0 + 1;
            int yc0 = min(max(y0, 0), 255), yc1 = min(max(y1, 0), 255);
            int xc0 = min(max(x0, 0), 255), xc1 = min(max(x1, 0), 255);
            float m00 = ((unsigned)y0 < 256u && (unsigned)x0 < 256u) ? 1.f : 0.f;
            float m01 = ((unsigned)y0 < 256u && (unsigned)x1 < 256u) ? 1.f : 0.f;
            float m10 = ((unsigned)y1 < 256u && (unsigned)x0 < 256u) ? 1.f : 0.f;
            float m11 = ((unsigned)y1 < 256u && (unsigned)x1 < 256u) ? 1.f : 0.f;
            // coords uniform across the wave -> each load is one contiguous 128B fetch
            float v00 = b2f(xb[(size_t)(yc0 * 256 + xc0) * 64]) * m00;
            float v01 = b2f(xb[(size_t)(yc0 * 256 + xc1) * 64]) * m01;
            float v10 = b2f(xb[(size_t)(yc1 * 256 + xc0) * 64]) * m10;
            float v11 = b2f(xb[(size_t)(yc1 * 256 + xc1) * 64]) * m11;
            float sv = (v00 * wx0 + v01 * wx1) * wy0 + (v10 * wx0 + v11 * wx1) * wy1;
            smem[pix * SBH + ci * 9 + k] = f2b(sv);
        }
    }
    __syncthreads();

    // ---- phase 2: thread = (cog 0..15, pixgrp 0..15); 8 co x 4 px accumulators ----
    int cog = t & 15, pixg = t >> 4;
    int pix0 = pixg * 4;
    float a0[8], a1[8], a2[8], a3[8];
    #pragma unroll
    for (int j = 0; j < 8; ++j) { a0[j] = 0.f; a1[j] = 0.f; a2[j] = 0.f; a3[j] = 0.f; }
    const u32* r0 = (const u32*)smem + (pix0 + 0) * SRU;
    const u32* r1 = (const u32*)smem + (pix0 + 1) * SRU;
    const u32* r2 = (const u32*)smem + (pix0 + 2) * SRU;
    const u32* r3 = (const u32*)smem + (pix0 + 3) * SRU;
    const float4* wt4 = (const float4*)wT;
    for (int kk = 0; kk < 144; ++kk) {
        int base = kk * 128 + cog * 2;
        float4 w0a = wt4[base];      float4 w0b = wt4[base + 1];
        float4 w1a = wt4[base + 32]; float4 w1b = wt4[base + 33];
        float4 w2a = wt4[base + 64]; float4 w2b = wt4[base + 65];
        float4 w3a = wt4[base + 96]; float4 w3b = wt4[base + 97];
        u32 pa, pb; float s0, s1, s2, s3;
        pa = r0[kk * 2]; pb = r0[kk * 2 + 1];
        s0 = blo(pa); s1 = bhi(pa); s2 = blo(pb); s3 = bhi(pb);
        FMA8(a0, s0, w0a, w0b); FMA8(a0, s1, w1a, w1b); FMA8(a0, s2, w2a, w2b); FMA8(a0, s3, w3a, w3b);
        pa = r1[kk * 2]; pb = r1[kk * 2 + 1];
        s0 = blo(pa); s1 = bhi(pa); s2 = blo(pb); s3 = bhi(pb);
        FMA8(a1, s0, w0a, w0b); FMA8(a1, s1, w1a, w1b); FMA8(a1, s2, w2a, w2b); FMA8(a1, s3, w3a, w3b);
        pa = r2[kk * 2]; pb = r2[kk * 2 + 1];
        s0 = blo(pa); s1 = bhi(pa); s2 = blo(pb); s3 = bhi(pb);
        FMA8(a2, s0, w0a, w0b); FMA8(a2, s1, w1a, w1b); FMA8(a2, s2, w2a, w2b); FMA8(a2, s3, w3a, w3b);
        pa = r3[kk * 2]; pb = r3[kk * 2 + 1];
        s0 = blo(pa); s1 = bhi(pa); s2 = blo(pb); s3 = bhi(pb);
        FMA8(a3, s0, w0a, w0b); FMA8(a3, s1, w1a, w1b); FMA8(a3, s2, w2a, w2b); FMA8(a3, s3, w3a, w3b);
    }
    // BN (bias folded into shift)
    int co0 = cog * 8;
    float sc[8], sh[8];
    #pragma unroll
    for (int c = 0; c < 8; ++c) { sc[c] = bnS[co0 + c]; sh[c] = bnT2[co0 + c]; }
    __syncthreads();                     // done reading S
    float* red = (float*)smem;           // reuse as [64][128] f32 (32 KB)
    #pragma unroll
    for (int c = 0; c < 8; ++c) red[(pix0 + 0) * 128 + co0 + c] = a0[c] * sc[c] + sh[c];
    #pragma unroll
    for (int c = 0; c < 8; ++c) red[(pix0 + 1) * 128 + co0 + c] = a1[c] * sc[c] + sh[c];
    #pragma unroll
    for (int c = 0; c < 8; ++c) red[(pix0 + 2) * 128 + co0 + c] = a2[c] * sc[c] + sh[c];
    #pragma unroll
    for (int c = 0; c < 8; ++c) red[(pix0 + 3) * 128 + co0 + c] = a3[c] * sc[c] + sh[c];
    __syncthreads();
    // coalesced bf16 store of out_pre (channels-last)
    bf16* op = out_pre + ((size_t)b * HHW + pixbase) * 128;
    for (int i = t; i < 8192; i += 256)
        op[i] = f2b(red[i]);
    // per-block pooled partial (fp32, pre-rounding values)
    if (t < 128) {
        float sum = 0.f;
        #pragma unroll
        for (int p = 0; p < 64; ++p) sum += red[p * 128 + t];
        part[((size_t)(b * 128 + t)) * 1024 + tile] = sum;
    }
}

// ---------------- K3a: reduce pooled partials ----------------
__global__ __launch_bounds__(256) void k_pool(const float* __restrict__ part, float* __restrict__ pooled) {
    int bco = blockIdx.x;   // 256 blocks
    int t = threadIdx.x;
    const float* p = part + (size_t)bco * 1024;
    float sum = 0.f;
    for (int i = t; i < 1024; i += 256) sum += p[i];
    __shared__ float r[256];
    r[t] = sum; __syncthreads();
    for (int ofs = 128; ofs > 0; ofs >>= 1) {
        if (t < ofs) r[t] += r[t + ofs];
        __syncthreads();
    }
    if (t == 0) pooled[bco] = r[0] * (1.f / 65536.f);
}

// ---------------- K3b: SE gate (1 block) ----------------
__global__ __launch_bounds__(256) void k_se(const float* __restrict__ pooled,
        const float* __restrict__ se_w, const float* __restrict__ se_b,
        const float* __restrict__ sg_, const float* __restrict__ sb_,
        const float* __restrict__ sm_, const float* __restrict__ sv_,
        const float* __restrict__ phi, float* __restrict__ dw) {
    __shared__ float tl[32];
    __shared__ float sp[16][128];
    __shared__ float pl[256];
    int t = threadIdx.x;
    pl[t] = pooled[t];
    __syncthreads();
    if (t < 32) {                       // t_vals: (b,r)
        int b = t >> 4, r = t & 15;
        float d = se_b[r];
        for (int c = 0; c < 128; ++c) d += pl[b * 128 + c] * se_w[r * 128 + c];
        float s = sg_[r] * rsqrtf(sv_[r] + 1e-5f);
        float xb = d * s + (sb_[r] - sm_[r] * s);
        tl[t] = 0.5f * xb * (1.f + erff(xb * 0.70710678118654752f));   // exact gelu
    }
    if (t >= 32 && t < 48) {            // softmax rows of phi
        int r = t - 32;
        float m = -1e30f;
        for (int c = 0; c < 128; ++c) m = fmaxf(m, phi[r * 128 + c]);
        float ssum = 0.f;
        for (int c = 0; c < 128; ++c) { float e = expf(phi[r * 128 + c] - m); sp[r][c] = e; ssum += e; }
        float inv = 1.f / ssum;
        for (int c = 0; c < 128; ++c) sp[r][c] *= inv;
    }
    __syncthreads();
    {
        int b = t >> 7, co = t & 127;
        float a = 0.f;
        #pragma unroll
        for (int r = 0; r < 16; ++r) a += tl[b * 16 + r] * sp[r][co];
        dw[t] = 1.f / (1.f + expf(-a));
    }
}

// ---------------- K4: gate * out_pre + BN(1x1 conv identity), relu, f32 NCHW ----------------
__global__ __launch_bounds__(256) void k_final(const bf16* __restrict__ xT,
        const bf16* __restrict__ out_pre, const float* __restrict__ dws2,
        const float* __restrict__ dsT, const float* __restrict__ dw,
        float* __restrict__ out) {
    __shared__ float xtile[64 * 68];     // 64 px x 64 ci, row pad to 68
    __shared__ float otile[64 * 129];    // 64 px x 128 co, row pad to 129 (stride%32==1 -> free)
    __shared__ float dwl[128], dsTl[128];
    int g = blockIdx.x;                  // 2048 blocks: b = g>>10, 64 pixels each
    int b = g >> 10;
    int pixbase = (g & 1023) << 6;
    int t = threadIdx.x;
    const bf16* xp = xT + ((size_t)b * HHW + pixbase) * 64;
    for (int i = t; i < 4096; i += 256)
        xtile[(i >> 6) * 68 + (i & 63)] = b2f(xp[i]);
    if (t < 128) { dwl[t] = dw[b * 128 + t]; dsTl[t] = dsT[t]; }
    __syncthreads();
    int co = t >> 1, half = t & 1;
    float4 wr[16];                       // 64 weights in regs (static-indexed)
    const float4* wp = (const float4*)(dws2 + co * 64);
    #pragma unroll
    for (int i = 0; i < 16; ++i) wr[i] = wp[i];
    float dwv = dwl[co], dst = dsTl[co];
    const bf16* opp = out_pre + ((size_t)b * HHW + pixbase) * 128 + co;
    for (int p0 = 0; p0 < 32; ++p0) {
        int p = half * 32 + p0;
        const float* xr = xtile + p * 68;
        float a = 0.f;
        #pragma unroll
        for (int i = 0; i < 16; ++i) {
            float4 xv = *(const float4*)(xr + i * 4);
            a += xv.x * wr[i].x + xv.y * wr[i].y + xv.z * wr[i].z + xv.w * wr[i].w;
        }
        float opre = b2f(opp[(size_t)p * 128]);
        float v = opre * dwv + a + dst;
        otile[p * 129 + co] = fmaxf(v, 0.f);
    }
    __syncthreads();
    float* ob = out + (size_t)b * 128 * HHW + pixbase;
    for (int i = t; i < 8192; i += 256) {
        int cco = i >> 6, pp = i & 63;
        ob[(size_t)cco * HHW + pp] = otile[pp * 129 + cco];
    }
}

extern "C" void kernel_launch(void* const* d_in, const int* in_sizes, int n_in,
                              void* d_out, int out_size, void* d_ws, size_t ws_size,
                              hipStream_t stream) {
    const float* x     = (const float*)d_in[0];
    const float* w_off = (const float*)d_in[1];
    const float* b_off = (const float*)d_in[2];
    const float* w_def = (const float*)d_in[3];
    const float* b_def = (const float*)d_in[4];
    const float* bng   = (const float*)d_in[5];
    const float* bnb   = (const float*)d_in[6];
    const float* bnm   = (const float*)d_in[7];
    const float* bnv   = (const float*)d_in[8];
    const float* se_w  = (const float*)d_in[9];
    const float* se_b  = (const float*)d_in[10];
    const float* sbg   = (const float*)d_in[11];
    const float* sbb   = (const float*)d_in[12];
    const float* sbm   = (const float*)d_in[13];
    const float* sbv   = (const float*)d_in[14];
    const float* phi   = (const float*)d_in[15];
    const float* ds_w  = (const float*)d_in[16];
    const float* dsg   = (const float*)d_in[17];
    const float* dsb   = (const float*)d_in[18];
    const float* dsm   = (const float*)d_in[19];
    const float* dsv   = (const float*)d_in[20];
    float* out = (float*)d_out;          // reference output is float32 (npz-size evidence)

    char* w = (char*)d_ws;
    bf16*  xT     = (bf16*)w;   w += 16777216;   // (B,HW,64) bf16
    float* offs   = (float*)w;  w += 9437184;    // (B,18,HW) f32
    float* wT     = (float*)w;  w += 294912;     // (576,128) f32
    float* wloff  = (float*)w;  w += 46080;      // (576,20) f32
    float* dws2   = (float*)w;  w += 32768;      // (128,64) f32
    float* bnS    = (float*)w;  w += 512;
    float* bnT2   = (float*)w;  w += 512;
    float* dsT    = (float*)w;  w += 512;
    bf16*  opre   = (bf16*)w;   w += 33554432;   // (B,HW,128) bf16
    float* part   = (float*)w;  w += 1048576;    // (256,1024) f32
    float* pooled = (float*)w;  w += 1024;
    float* dwv    = (float*)w;  w += 1024;

    hipLaunchKernelGGL(k_prep_x, dim3(2048), dim3(256), 0, stream, x, xT);
    hipLaunchKernelGGL(k_prep_w, dim3(32), dim3(256), 0, stream, w_off, w_def, b_def,
                       bng, bnb, bnm, bnv, ds_w, dsg, dsb, dsm, dsv,
                       wT, wloff, dws2, bnS, bnT2, dsT);
    hipLaunchKernelGGL(k_off, dim3(512), dim3(256), 0, stream, x, wloff, b_off, offs);
    hipLaunchKernelGGL(k_deform, dim3(2048), dim3(256), 0, stream, xT, offs, wT, bnS, bnT2, opre, part);
    hipLaunchKernelGGL(k_pool, dim3(256), dim3(256), 0, stream, part, pooled);
    hipLaunchKernelGGL(k_se, dim3(1), dim3(256), 0, stream, pooled, se_w, se_b, sbg, sbb, sbm, sbv, phi, dwv);
    hipLaunchKernelGGL(k_final, dim3(2048), dim3(256), 0, stream, xT, opre, dws2, dsT, dwv, out);
}

// Round 5
// 570.877 us; speedup vs baseline: 1.3201x; 1.3201x over previous
//
#include <hip/hip_runtime.h>
#include <hip/hip_bf16.h>

typedef __hip_bfloat16 bf16;
typedef unsigned int u32;
typedef __attribute__((ext_vector_type(8))) short bf16x8;  // 8 bf16 = 4 VGPRs (MFMA A/B frag)
typedef __attribute__((ext_vector_type(4))) float f32x4;   // MFMA C/D frag

#define HHW 65536
#define SBH 584            // S row stride in bf16: 1168 B, 16B-aligned; 292 dw ≡ 4 mod 32 -> uniform 8-phase b128 tiling
#define REDW 132           // staging row stride in f32 (132%32==4 -> 2-way max on frag writes)

__device__ __forceinline__ float b2f(bf16 v) { return __bfloat162float(v); }
__device__ __forceinline__ bf16  f2b(float v) { return __float2bfloat16(v); }

// ---------------- K0: transpose x (B,64,H,W) f32 -> xT (B,HW,64) bf16 ----------------
__global__ __launch_bounds__(256) void k_prep_x(const float* __restrict__ x, bf16* __restrict__ xT) {
    __shared__ bf16 tile[64][66];   // +2 pad: conflict-free transposed writes
    int g = blockIdx.x;             // 2048 blocks: b = g>>10, 64 pixels each
    int b = g >> 10;
    int pixbase = (g & 1023) << 6;
    int t = threadIdx.x;
    int pix = t & 63, ci0 = t >> 6;
    const float* xb = x + ((size_t)b * 64) * HHW + pixbase + pix;
    for (int ci = ci0; ci < 64; ci += 4)
        tile[pix][ci] = f2b(xb[(size_t)ci * HHW]);
    __syncthreads();
    bf16* dst = xT + ((size_t)b * HHW + pixbase) * 64;
    for (int i = t; i < 4096; i += 256)
        dst[i] = tile[i >> 6][i & 63];
}

// ---------------- K0b: weight/const prep ----------------
__global__ __launch_bounds__(256) void k_prep_w(
        const float* __restrict__ w_off, const float* __restrict__ w_def, const float* __restrict__ b_def,
        const float* __restrict__ bng, const float* __restrict__ bnb, const float* __restrict__ bnm, const float* __restrict__ bnv,
        const float* __restrict__ ds_w, const float* __restrict__ dsg, const float* __restrict__ dsb,
        const float* __restrict__ dsm, const float* __restrict__ dsv,
        bf16* __restrict__ Wf, float* __restrict__ wloff, float* __restrict__ dws2,
        float* __restrict__ bnS, float* __restrict__ bnT2, float* __restrict__ dsT) {
    int tid = blockIdx.x * 256 + threadIdx.x;   // 32 blocks -> 8192 threads
    // Wf[ct][ks][lane][j]: MFMA B-fragment order. col=ct*16+(lane&15), k=ks*32+(lane>>4)*8+j
    // (k index == w_def inner index ci*9+ky*3+kx, matching S's column order)
    for (int i = tid; i < 8 * 18 * 64 * 8; i += 8192) {
        int j = i & 7, lane = (i >> 3) & 63;
        int rem = i >> 9;                // ct*18 + ks
        int ks = rem % 18, ct = rem / 18;
        int co = ct * 16 + (lane & 15);
        int k  = ks * 32 + (lane >> 4) * 8 + j;
        Wf[i] = f2b(w_def[co * 576 + k]);
    }
    // wloff[kci][20] = w_off[j][kci] padded with zeros (j<18)
    for (int i = tid; i < 576 * 20; i += 8192) {
        int kci = i / 20, j = i - kci * 20;
        wloff[i] = (j < 18) ? w_off[j * 576 + kci] : 0.f;
    }
    // dws2[co][ci] = ds_w * ds_bn_scale  (fold BN scale into 1x1 weights)
    if (tid < 8192) {
        int co = tid >> 6;
        float s2 = dsg[co] * rsqrtf(dsv[co] + 1e-5f);
        dws2[tid] = ds_w[tid] * s2;
    }
    if (tid < 128) {
        float s = bng[tid] * rsqrtf(bnv[tid] + 1e-5f);
        bnS[tid] = s;
        bnT2[tid] = (b_def[tid] - bnm[tid]) * s + bnb[tid];  // fold conv bias into BN shift
        float s2 = dsg[tid] * rsqrtf(dsv[tid] + 1e-5f);
        dsT[tid] = dsb[tid] - dsm[tid] * s2;
    }
}

// ---------------- K1: offset conv 3x3, 64 -> 18 (pad=1), f32 ----------------
__global__ __launch_bounds__(256) void k_off(const float* __restrict__ x,
        const float* __restrict__ wloff, const float* __restrict__ b_off,
        float* __restrict__ off) {
    int g = blockIdx.x;               // 512 blocks = b*256 + h
    int b = g >> 8, h = g & 255;
    int t = threadIdx.x;              // w
    float acc[20];
    #pragma unroll
    for (int j = 0; j < 20; ++j) acc[j] = 0.f;
    const float* xb = x + ((size_t)b * 64) * HHW;
    for (int ci = 0; ci < 64; ++ci) {
        const float* xc = xb + (size_t)ci * HHW;
        #pragma unroll
        for (int ky = 0; ky < 3; ++ky) {
            int y = h + ky - 1;
            if ((unsigned)y >= 256u) continue;
            const float* row = xc + y * 256;
            float v0 = (t >= 1)   ? row[t - 1] : 0.f;
            float v1 = row[t];
            float v2 = (t <= 254) ? row[t + 1] : 0.f;
            const float4* wr = (const float4*)(wloff + (ci * 9 + ky * 3) * 20);
            #pragma unroll
            for (int q = 0; q < 5; ++q) {
                float4 wv = wr[q];
                acc[q*4+0] += v0 * wv.x; acc[q*4+1] += v0 * wv.y;
                acc[q*4+2] += v0 * wv.z; acc[q*4+3] += v0 * wv.w;
            }
            #pragma unroll
            for (int q = 0; q < 5; ++q) {
                float4 wv = wr[5 + q];
                acc[q*4+0] += v1 * wv.x; acc[q*4+1] += v1 * wv.y;
                acc[q*4+2] += v1 * wv.z; acc[q*4+3] += v1 * wv.w;
            }
            #pragma unroll
            for (int q = 0; q < 5; ++q) {
                float4 wv = wr[10 + q];
                acc[q*4+0] += v2 * wv.x; acc[q*4+1] += v2 * wv.y;
                acc[q*4+2] += v2 * wv.z; acc[q*4+3] += v2 * wv.w;
            }
        }
    }
    float* ob = off + ((size_t)b * 18) * HHW + h * 256 + t;
    #pragma unroll
    for (int j = 0; j < 18; ++j) ob[(size_t)j * HHW] = acc[j] + b_off[j];
}

// ---------------- K2: deformable conv (MFMA) + BN + pooled partials ----------------
// block = 64 pixels; phase 1: bilinear sample S[64][576] bf16 into LDS;
// phase 2: 4 waves x (16px x 128co) via mfma_f32_16x16x32_bf16, 18 K-steps x 8 co-tiles
__global__ __launch_bounds__(256) void k_deform(const bf16* __restrict__ xT,
        const float* __restrict__ off, const bf16* __restrict__ Wf,
        const float* __restrict__ bnS, const float* __restrict__ bnT2,
        bf16* __restrict__ out_pre, float* __restrict__ part) {
    __shared__ bf16 smem[64 * SBH];      // 73 KB -> 2 blocks/CU
    int blk = blockIdx.x;                // 2048 = 2 * 1024
    int b = blk >> 10;
    int tile = blk & 1023;
    int pixbase = tile << 6;             // 64 px, contiguous within one row
    int h = pixbase >> 8;
    int w0 = pixbase & 255;
    int t = threadIdx.x;

    // ---- phase 1: bilinear sampling into S[pix][ci*9+k] (bf16) ----
    {
        int ci = t & 63, pg = t >> 6;    // pg uniform per wave
        const bf16* xb = xT + ((size_t)b * HHW) * 64 + ci;
        const float* offb = off + ((size_t)b * 18) * HHW + pixbase;
        for (int it = 0; it < 144; ++it) {
            int pk = it * 4 + pg;        // (pix,k) pair, 0..575
            int pix = pk / 9;
            int k = pk - pix * 9;
            int ky = k / 3, kx = k - ky * 3;
            float dy = offb[(size_t)(2 * k) * HHW + pix];
            float dx = offb[(size_t)(2 * k + 1) * HHW + pix];
            float py = (float)(h + ky - 1) + dy;
            float px = (float)(w0 + pix + kx - 1) + dx;
            float fy = floorf(py), fx = floorf(px);
            int y0 = (int)fy, x0 = (int)fx;
            float wy1 = py - fy, wx1 = px - fx;
            float wy0 = 1.f - wy1, wx0 = 1.f - wx1;
            int y1 = y0 + 1, x1 = x0 + 1;
            int yc0 = min(max(y0, 0), 255), yc1 = min(max(y1, 0), 255);
            int xc0 = min(max(x0, 0), 255), xc1 = min(max(x1, 0), 255);
            float m00 = ((unsigned)y0 < 256u && (unsigned)x0 < 256u) ? 1.f : 0.f;
            float m01 = ((unsigned)y0 < 256u && (unsigned)x1 < 256u) ? 1.f : 0.f;
            float m10 = ((unsigned)y1 < 256u && (unsigned)x0 < 256u) ? 1.f : 0.f;
            float m11 = ((unsigned)y1 < 256u && (unsigned)x1 < 256u) ? 1.f : 0.f;
            // coords uniform across the wave -> each load is one contiguous 128B fetch
            float v00 = b2f(xb[(size_t)(yc0 * 256 + xc0) * 64]) * m00;
            float v01 = b2f(xb[(size_t)(yc0 * 256 + xc1) * 64]) * m01;
            float v10 = b2f(xb[(size_t)(yc1 * 256 + xc0) * 64]) * m10;
            float v11 = b2f(xb[(size_t)(yc1 * 256 + xc1) * 64]) * m11;
            float sv = (v00 * wx0 + v01 * wx1) * wy0 + (v10 * wx0 + v11 * wx1) * wy1;
            smem[pix * SBH + ci * 9 + k] = f2b(sv);
        }
    }
    __syncthreads();

    // ---- phase 2: MFMA GEMM. wave wid: px [wid*16, wid*16+16); 8 co-tiles of 16 ----
    int wid = t >> 6, l = t & 63;
    int wp = wid << 4;
    int lr = l & 15, lg = l >> 4;        // A row / D col; k-group
    f32x4 acc[8];
    #pragma unroll
    for (int ct = 0; ct < 8; ++ct) acc[ct] = (f32x4){0.f, 0.f, 0.f, 0.f};
    const bf16* arow = smem + (wp + lr) * SBH + lg * 8;
    const bf16* wbase = Wf + l * 8;
    #pragma unroll
    for (int ks = 0; ks < 18; ++ks) {
        bf16x8 af = *(const bf16x8*)(arow + ks * 32);
        #pragma unroll
        for (int ct = 0; ct < 8; ++ct) {
            bf16x8 bfr = *(const bf16x8*)(wbase + (ct * 18 + ks) * 512);
            acc[ct] = __builtin_amdgcn_mfma_f32_16x16x32_bf16(af, bfr, acc[ct], 0, 0, 0);
        }
    }
    __syncthreads();                     // all waves done reading S before staging reuse
    // ---- epilogue: BN, stage to LDS, coalesced stores + pooled partials ----
    float* red = (float*)smem;           // [64][REDW] f32 (33.8 KB)
    #pragma unroll
    for (int ct = 0; ct < 8; ++ct) {
        int co = ct * 16 + lr;           // D col = lane&15
        float sc = bnS[co], sh = bnT2[co];
        #pragma unroll
        for (int r = 0; r < 4; ++r) {    // D row = (lane>>4)*4 + r
            int m = lg * 4 + r;
            red[(wp + m) * REDW + co] = acc[ct][r] * sc + sh;
        }
    }
    __syncthreads();
    bf16* op = out_pre + ((size_t)b * HHW + pixbase) * 128;
    for (int i = t; i < 8192; i += 256)
        op[i] = f2b(red[(i >> 7) * REDW + (i & 127)]);
    if (t < 128) {
        float sum = 0.f;
        #pragma unroll
        for (int p = 0; p < 64; ++p) sum += red[p * REDW + t];
        part[((size_t)(b * 128 + t)) * 1024 + tile] = sum;
    }
}

// ---------------- K3a: reduce pooled partials ----------------
__global__ __launch_bounds__(256) void k_pool(const float* __restrict__ part, float* __restrict__ pooled) {
    int bco = blockIdx.x;   // 256 blocks
    int t = threadIdx.x;
    const float* p = part + (size_t)bco * 1024;
    float sum = 0.f;
    for (int i = t; i < 1024; i += 256) sum += p[i];
    __shared__ float r[256];
    r[t] = sum; __syncthreads();
    for (int ofs = 128; ofs > 0; ofs >>= 1) {
        if (t < ofs) r[t] += r[t + ofs];
        __syncthreads();
    }
    if (t == 0) pooled[bco] = r[0] * (1.f / 65536.f);
}

// ---------------- K3b: SE gate (1 block) ----------------
__global__ __launch_bounds__(256) void k_se(const float* __restrict__ pooled,
        const float* __restrict__ se_w, const float* __restrict__ se_b,
        const float* __restrict__ sg_, const float* __restrict__ sb_,
        const float* __restrict__ sm_, const float* __restrict__ sv_,
        const float* __restrict__ phi, float* __restrict__ dw) {
    __shared__ float tl[32];
    __shared__ float sp[16][128];
    __shared__ float pl[256];
    int t = threadIdx.x;
    pl[t] = pooled[t];
    __syncthreads();
    if (t < 32) {                       // t_vals: (b,r)
        int b = t >> 4, r = t & 15;
        float d = se_b[r];
        for (int c = 0; c < 128; ++c) d += pl[b * 128 + c] * se_w[r * 128 + c];
        float s = sg_[r] * rsqrtf(sv_[r] + 1e-5f);
        float xb = d * s + (sb_[r] - sm_[r] * s);
        tl[t] = 0.5f * xb * (1.f + erff(xb * 0.70710678118654752f));   // exact gelu
    }
    if (t >= 32 && t < 48) {            // softmax rows of phi
        int r = t - 32;
        float m = -1e30f;
        for (int c = 0; c < 128; ++c) m = fmaxf(m, phi[r * 128 + c]);
        float ssum = 0.f;
        for (int c = 0; c < 128; ++c) { float e = expf(phi[r * 128 + c] - m); sp[r][c] = e; ssum += e; }
        float inv = 1.f / ssum;
        for (int c = 0; c < 128; ++c) sp[r][c] *= inv;
    }
    __syncthreads();
    {
        int b = t >> 7, co = t & 127;
        float a = 0.f;
        #pragma unroll
        for (int r = 0; r < 16; ++r) a += tl[b * 16 + r] * sp[r][co];
        dw[t] = 1.f / (1.f + expf(-a));
    }
}

// ---------------- K4: gate * out_pre + BN(1x1 conv identity), relu, f32 NCHW ----------------
__global__ __launch_bounds__(256) void k_final(const bf16* __restrict__ xT,
        const bf16* __restrict__ out_pre, const float* __restrict__ dws2,
        const float* __restrict__ dsT, const float* __restrict__ dw,
        float* __restrict__ out) {
    __shared__ float xtile[64 * 68];     // 64 px x 64 ci, row pad to 68
    __shared__ float otile[64 * 129];    // 64 px x 128 co, row pad to 129 (stride%32==1 -> free)
    __shared__ float dwl[128], dsTl[128];
    int g = blockIdx.x;                  // 2048 blocks: b = g>>10, 64 pixels each
    int b = g >> 10;
    int pixbase = (g & 1023) << 6;
    int t = threadIdx.x;
    const bf16* xp = xT + ((size_t)b * HHW + pixbase) * 64;
    for (int i = t; i < 4096; i += 256)
        xtile[(i >> 6) * 68 + (i & 63)] = b2f(xp[i]);
    if (t < 128) { dwl[t] = dw[b * 128 + t]; dsTl[t] = dsT[t]; }
    __syncthreads();
    int co = t >> 1, half = t & 1;
    float4 wr[16];                       // 64 weights in regs (static-indexed)
    const float4* wp = (const float4*)(dws2 + co * 64);
    #pragma unroll
    for (int i = 0; i < 16; ++i) wr[i] = wp[i];
    float dwv = dwl[co], dst = dsTl[co];
    const bf16* opp = out_pre + ((size_t)b * HHW + pixbase) * 128 + co;
    for (int p0 = 0; p0 < 32; ++p0) {
        int p = half * 32 + p0;
        const float* xr = xtile + p * 68;
        float a = 0.f;
        #pragma unroll
        for (int i = 0; i < 16; ++i) {
            float4 xv = *(const float4*)(xr + i * 4);
            a += xv.x * wr[i].x + xv.y * wr[i].y + xv.z * wr[i].z + xv.w * wr[i].w;
        }
        float opre = b2f(opp[(size_t)p * 128]);
        float v = opre * dwv + a + dst;
        otile[p * 129 + co] = fmaxf(v, 0.f);
    }
    __syncthreads();
    float* ob = out + (size_t)b * 128 * HHW + pixbase;
    for (int i = t; i < 8192; i += 256) {
        int cco = i >> 6, pp = i & 63;
        ob[(size_t)cco * HHW + pp] = otile[pp * 129 + cco];
    }
}

extern "C" void kernel_launch(void* const* d_in, const int* in_sizes, int n_in,
                              void* d_out, int out_size, void* d_ws, size_t ws_size,
                              hipStream_t stream) {
    const float* x     = (const float*)d_in[0];
    const float* w_off = (const float*)d_in[1];
    const float* b_off = (const float*)d_in[2];
    const float* w_def = (const float*)d_in[3];
    const float* b_def = (const float*)d_in[4];
    const float* bng   = (const float*)d_in[5];
    const float* bnb   = (const float*)d_in[6];
    const float* bnm   = (const float*)d_in[7];
    const float* bnv   = (const float*)d_in[8];
    const float* se_w  = (const float*)d_in[9];
    const float* se_b  = (const float*)d_in[10];
    const float* sbg   = (const float*)d_in[11];
    const float* sbb   = (const float*)d_in[12];
    const float* sbm   = (const float*)d_in[13];
    const float* sbv   = (const float*)d_in[14];
    const float* phi   = (const float*)d_in[15];
    const float* ds_w  = (const float*)d_in[16];
    const float* dsg   = (const float*)d_in[17];
    const float* dsb   = (const float*)d_in[18];
    const float* dsm   = (const float*)d_in[19];
    const float* dsv   = (const float*)d_in[20];
    float* out = (float*)d_out;          // reference output is float32

    char* w = (char*)d_ws;
    bf16*  xT     = (bf16*)w;   w += 16777216;   // (B,HW,64) bf16
    float* offs   = (float*)w;  w += 9437184;    // (B,18,HW) f32
    bf16*  Wf     = (bf16*)w;   w += 147456;     // MFMA-fragment-ordered weights, bf16
    float* wloff  = (float*)w;  w += 46080;      // (576,20) f32
    float* dws2   = (float*)w;  w += 32768;      // (128,64) f32
    float* bnS    = (float*)w;  w += 512;
    float* bnT2   = (float*)w;  w += 512;
    float* dsT    = (float*)w;  w += 512;
    bf16*  opre   = (bf16*)w;   w += 33554432;   // (B,HW,128) bf16
    float* part   = (float*)w;  w += 1048576;    // (256,1024) f32
    float* pooled = (float*)w;  w += 1024;
    float* dwv    = (float*)w;  w += 1024;

    hipLaunchKernelGGL(k_prep_x, dim3(2048), dim3(256), 0, stream, x, xT);
    hipLaunchKernelGGL(k_prep_w, dim3(32), dim3(256), 0, stream, w_off, w_def, b_def,
                       bng, bnb, bnm, bnv, ds_w, dsg, dsb, dsm, dsv,
                       Wf, wloff, dws2, bnS, bnT2, dsT);
    hipLaunchKernelGGL(k_off, dim3(512), dim3(256), 0, stream, x, wloff, b_off, offs);
    hipLaunchKernelGGL(k_deform, dim3(2048), dim3(256), 0, stream, xT, offs, Wf, bnS, bnT2, opre, part);
    hipLaunchKernelGGL(k_pool, dim3(256), dim3(256), 0, stream, part, pooled);
    hipLaunchKernelGGL(k_se, dim3(1), dim3(256), 0, stream, pooled, se_w, se_b, sbg, sbb, sbm, sbv, phi, dwv);
    hipLaunchKernelGGL(k_final, dim3(2048), dim3(256), 0, stream, xT, opre, dws2, dsT, dwv, out);
}

// Round 6
// 442.745 us; speedup vs baseline: 1.7021x; 1.2894x over previous
//
#include <hip/hip_runtime.h>
#include <hip/hip_bf16.h>

typedef __hip_bfloat16 bf16;
typedef unsigned int u32;
typedef __attribute__((ext_vector_type(8))) short bf16x8;  // 8 bf16 = 4 VGPRs (MFMA A/B frag)
typedef __attribute__((ext_vector_type(4))) float f32x4;   // MFMA C/D frag

#define HHW 65536
#define SBH 584            // S row stride in bf16 (292 dw ≡ 4 mod 32 -> 2-way max on b128 reads = free)
#define SWU 292            // S row stride in u32
#define REDW 132           // staging row stride in f32

__device__ __forceinline__ float b2f(bf16 v) { return __bfloat162float(v); }
__device__ __forceinline__ bf16  f2b(float v) { return __float2bfloat16(v); }
__device__ __forceinline__ float blo(u32 p) { return __uint_as_float(p << 16); }
__device__ __forceinline__ float bhi(u32 p) { return __uint_as_float(p & 0xffff0000u); }
__device__ __forceinline__ u32 pack2(float lo, float hi) {
    bf16 a = f2b(lo), c = f2b(hi);
    unsigned short ua, uc;
    __builtin_memcpy(&ua, &a, 2); __builtin_memcpy(&uc, &c, 2);
    return (u32)ua | ((u32)uc << 16);
}

// ---------------- K0: x transpose (blocks 0..2047) + weight/const prep (blocks 2048..2079) ----------------
__global__ __launch_bounds__(256) void k_prep(const float* __restrict__ x, bf16* __restrict__ xT,
        const float* __restrict__ w_off, const float* __restrict__ w_def, const float* __restrict__ b_def,
        const float* __restrict__ bng, const float* __restrict__ bnb, const float* __restrict__ bnm, const float* __restrict__ bnv,
        const float* __restrict__ ds_w, const float* __restrict__ dsg, const float* __restrict__ dsb,
        const float* __restrict__ dsm, const float* __restrict__ dsv,
        bf16* __restrict__ Wf, float* __restrict__ wloff, float* __restrict__ dws2,
        float* __restrict__ bnS, float* __restrict__ bnT2, float* __restrict__ dsT) {
    __shared__ bf16 tile[64][66];
    int g = blockIdx.x;
    int t = threadIdx.x;
    if (g < 2048) {                      // transpose x (B,64,H,W) f32 -> xT (B,HW,64) bf16
        int b = g >> 10;
        int pixbase = (g & 1023) << 6;
        int pix = t & 63, ci0 = t >> 6;
        const float* xb = x + ((size_t)b * 64) * HHW + pixbase + pix;
        for (int ci = ci0; ci < 64; ci += 4)
            tile[pix][ci] = f2b(xb[(size_t)ci * HHW]);
        __syncthreads();
        bf16* dst = xT + ((size_t)b * HHW + pixbase) * 64;
        for (int i = t; i < 4096; i += 256)
            dst[i] = tile[i >> 6][i & 63];
        return;
    }
    int tid = (g - 2048) * 256 + t;      // 8192 threads
    // Wf[ct][ks][lane][j]: B-frag order; K = ks*32+(lane>>4)*8+j maps to (ci=K&63, kk=K>>6)
    // matching S's K-major column order k*64+ci.
    for (int i = tid; i < 8 * 18 * 64 * 8; i += 8192) {
        int j = i & 7, lane = (i >> 3) & 63;
        int rem = i >> 9;                // ct*18 + ks
        int ks = rem % 18, ct = rem / 18;
        int co = ct * 16 + (lane & 15);
        int K  = ks * 32 + ((lane >> 4) << 3) + j;
        int ci = K & 63, kk = K >> 6;
        Wf[i] = f2b(w_def[co * 576 + ci * 9 + kk]);
    }
    // wloff[kci][20] = w_off[j][kci] padded with zeros (j<18)
    for (int i = tid; i < 576 * 20; i += 8192) {
        int kci = i / 20, j = i - kci * 20;
        wloff[i] = (j < 18) ? w_off[j * 576 + kci] : 0.f;
    }
    if (tid < 8192) {
        int co = tid >> 6;
        float s2 = dsg[co] * rsqrtf(dsv[co] + 1e-5f);
        dws2[tid] = ds_w[tid] * s2;      // fold ds-BN scale into 1x1 weights
    }
    if (tid < 128) {
        float s = bng[tid] * rsqrtf(bnv[tid] + 1e-5f);
        bnS[tid] = s;
        bnT2[tid] = (b_def[tid] - bnm[tid]) * s + bnb[tid];
        float s2 = dsg[tid] * rsqrtf(dsv[tid] + 1e-5f);
        dsT[tid] = dsb[tid] - dsm[tid] * s2;
    }
}

// ---------------- K1: offset conv 3x3 -> per-(pix,tap) sample records ----------------
// rec r = k*64 + pix within tile: orec = 4 corner dword-offsets, wrec = 4 mask-folded weights
__global__ __launch_bounds__(256) void k_off(const float* __restrict__ x,
        const float* __restrict__ wloff, const float* __restrict__ b_off,
        uint4* __restrict__ orec, float4* __restrict__ wrec) {
    int g = blockIdx.x;               // 512 blocks = b*256 + h
    int b = g >> 8, h = g & 255;
    int t = threadIdx.x;              // w
    float acc[20];
    #pragma unroll
    for (int j = 0; j < 20; ++j) acc[j] = 0.f;
    const float* xb = x + ((size_t)b * 64) * HHW;
    for (int ci = 0; ci < 64; ++ci) {
        const float* xc = xb + (size_t)ci * HHW;
        #pragma unroll
        for (int ky = 0; ky < 3; ++ky) {
            int y = h + ky - 1;
            if ((unsigned)y >= 256u) continue;
            const float* row = xc + y * 256;
            float v0 = (t >= 1)   ? row[t - 1] : 0.f;
            float v1 = row[t];
            float v2 = (t <= 254) ? row[t + 1] : 0.f;
            const float4* wr = (const float4*)(wloff + (ci * 9 + ky * 3) * 20);
            #pragma unroll
            for (int q = 0; q < 5; ++q) {
                float4 wv = wr[q];
                acc[q*4+0] += v0 * wv.x; acc[q*4+1] += v0 * wv.y;
                acc[q*4+2] += v0 * wv.z; acc[q*4+3] += v0 * wv.w;
            }
            #pragma unroll
            for (int q = 0; q < 5; ++q) {
                float4 wv = wr[5 + q];
                acc[q*4+0] += v1 * wv.x; acc[q*4+1] += v1 * wv.y;
                acc[q*4+2] += v1 * wv.z; acc[q*4+3] += v1 * wv.w;
            }
            #pragma unroll
            for (int q = 0; q < 5; ++q) {
                float4 wv = wr[10 + q];
                acc[q*4+0] += v2 * wv.x; acc[q*4+1] += v2 * wv.y;
                acc[q*4+2] += v2 * wv.z; acc[q*4+3] += v2 * wv.w;
            }
        }
    }
    // epilogue: emit 9 sample records for this pixel
    int tile = (h << 2) + (t >> 6);
    int pix  = t & 63;
    size_t rbase = ((size_t)(b * 1024 + tile)) * 576;
    #pragma unroll
    for (int k = 0; k < 9; ++k) {
        int ky = k / 3, kx = k - ky * 3;
        float dy = acc[2 * k]     + b_off[2 * k];
        float dx = acc[2 * k + 1] + b_off[2 * k + 1];
        float py = (float)(h + ky - 1) + dy;
        float px = (float)(t + kx - 1) + dx;
        float fy = floorf(py), fx = floorf(px);
        int y0 = (int)fy, x0 = (int)fx;
        float wy1 = py - fy, wx1 = px - fx;
        float wy0 = 1.f - wy1, wx0 = 1.f - wx1;
        int y1 = y0 + 1, x1 = x0 + 1;
        int yc0 = min(max(y0, 0), 255), yc1 = min(max(y1, 0), 255);
        int xc0 = min(max(x0, 0), 255), xc1 = min(max(x1, 0), 255);
        float m0 = ((unsigned)y0 < 256u) ? 1.f : 0.f;
        float m1 = ((unsigned)y1 < 256u) ? 1.f : 0.f;
        float n0 = ((unsigned)x0 < 256u) ? 1.f : 0.f;
        float n1 = ((unsigned)x1 < 256u) ? 1.f : 0.f;
        uint4 o;
        o.x = ((u32)(yc0 * 256 + xc0)) << 5;   // dword offset into xT batch plane
        o.y = ((u32)(yc0 * 256 + xc1)) << 5;
        o.z = ((u32)(yc1 * 256 + xc0)) << 5;
        o.w = ((u32)(yc1 * 256 + xc1)) << 5;
        float4 wv;
        wv.x = wy0 * wx0 * m0 * n0;
        wv.y = wy0 * wx1 * m0 * n1;
        wv.z = wy1 * wx0 * m1 * n0;
        wv.w = wy1 * wx1 * m1 * n1;
        orec[rbase + k * 64 + pix] = o;
        wrec[rbase + k * 64 + pix] = wv;
    }
}

// ---------------- K2: deformable conv (MFMA) + BN + pooled partials ----------------
// phase 1: table-driven bilinear sampling -> S[64][k*64+ci] bf16 (2 ci per lane, u32 path)
// phase 2: 4 waves x (16px x 128co) via mfma_f32_16x16x32_bf16
__global__ __launch_bounds__(256) void k_deform(const bf16* __restrict__ xT,
        const uint4* __restrict__ orec, const float4* __restrict__ wrec,
        const bf16* __restrict__ Wf,
        const float* __restrict__ bnS, const float* __restrict__ bnT2,
        bf16* __restrict__ out_pre, float* __restrict__ part) {
    __shared__ bf16 smem[64 * SBH];      // 73 KB -> 2 blocks/CU
    int blk = blockIdx.x;                // 2048 = 2 * 1024
    int b = blk >> 10;
    int tile = blk & 1023;
    int pixbase = tile << 6;
    int t = threadIdx.x;
    int wid = t >> 6, l = t & 63;

    // ---- phase 1: sampling. 8 records per iteration (4 waves x 2 halves) ----
    {
        int cig = l & 31, hf = l >> 5;
        size_t rbase = ((size_t)(b * 1024 + tile)) * 576;
        const uint4*  orc = orec + rbase;
        const float4* wrc = wrec + rbase;
        const u32* xw = (const u32*)xT + (size_t)b * (HHW * 32);
        u32* sw = (u32*)smem;
        #pragma unroll 4
        for (int it = 0; it < 72; ++it) {
            int r = (it << 3) + (wid << 1) + hf;
            uint4  o  = orc[r];
            float4 wv = wrc[r];
            u32 p00 = xw[o.x + cig];
            u32 p01 = xw[o.y + cig];
            u32 p10 = xw[o.z + cig];
            u32 p11 = xw[o.w + cig];
            float lo = blo(p00)*wv.x + blo(p01)*wv.y + blo(p10)*wv.z + blo(p11)*wv.w;
            float hi = bhi(p00)*wv.x + bhi(p01)*wv.y + bhi(p10)*wv.z + bhi(p11)*wv.w;
            int k9 = r >> 6, pix = r & 63;
            sw[pix * SWU + (k9 << 5) + cig] = pack2(lo, hi);
        }
    }
    __syncthreads();

    // ---- phase 2: MFMA GEMM. wave wid: px [wid*16, ..+16); 8 co-tiles of 16 ----
    int wp = wid << 4;
    int lr = l & 15, lg = l >> 4;
    f32x4 acc[8];
    #pragma unroll
    for (int ct = 0; ct < 8; ++ct) acc[ct] = (f32x4){0.f, 0.f, 0.f, 0.f};
    const bf16* arow = smem + (wp + lr) * SBH + lg * 8;
    const bf16* wbase = Wf + l * 8;
    #pragma unroll
    for (int ks = 0; ks < 18; ++ks) {
        bf16x8 af = *(const bf16x8*)(arow + ks * 32);
        #pragma unroll
        for (int ct = 0; ct < 8; ++ct) {
            bf16x8 bfr = *(const bf16x8*)(wbase + (ct * 18 + ks) * 512);
            acc[ct] = __builtin_amdgcn_mfma_f32_16x16x32_bf16(af, bfr, acc[ct], 0, 0, 0);
        }
    }
    __syncthreads();                     // all waves done reading S before staging reuse
    // ---- epilogue: BN, stage to LDS, coalesced stores + pooled partials ----
    float* red = (float*)smem;           // [64][REDW] f32
    #pragma unroll
    for (int ct = 0; ct < 8; ++ct) {
        int co = ct * 16 + lr;
        float sc = bnS[co], sh = bnT2[co];
        #pragma unroll
        for (int r = 0; r < 4; ++r) {
            int m = lg * 4 + r;
            red[(wp + m) * REDW + co] = acc[ct][r] * sc + sh;
        }
    }
    __syncthreads();
    bf16* op = out_pre + ((size_t)b * HHW + pixbase) * 128;
    for (int i = t; i < 8192; i += 256)
        op[i] = f2b(red[(i >> 7) * REDW + (i & 127)]);
    if (t < 128) {
        float sum = 0.f;
        #pragma unroll
        for (int p = 0; p < 64; ++p) sum += red[p * REDW + t];
        part[((size_t)(b * 128 + t)) * 1024 + tile] = sum;
    }
}

// ---------------- K3a: reduce pooled partials ----------------
__global__ __launch_bounds__(256) void k_pool(const float* __restrict__ part, float* __restrict__ pooled) {
    int bco = blockIdx.x;   // 256 blocks
    int t = threadIdx.x;
    const float* p = part + (size_t)bco * 1024;
    float sum = 0.f;
    for (int i = t; i < 1024; i += 256) sum += p[i];
    __shared__ float r[256];
    r[t] = sum; __syncthreads();
    for (int ofs = 128; ofs > 0; ofs >>= 1) {
        if (t < ofs) r[t] += r[t + ofs];
        __syncthreads();
    }
    if (t == 0) pooled[bco] = r[0] * (1.f / 65536.f);
}

// ---------------- K3b: SE gate (1 block) ----------------
__global__ __launch_bounds__(256) void k_se(const float* __restrict__ pooled,
        const float* __restrict__ se_w, const float* __restrict__ se_b,
        const float* __restrict__ sg_, const float* __restrict__ sb_,
        const float* __restrict__ sm_, const float* __restrict__ sv_,
        const float* __restrict__ phi, float* __restrict__ dw) {
    __shared__ float tl[32];
    __shared__ float sp[16][128];
    __shared__ float pl[256];
    int t = threadIdx.x;
    pl[t] = pooled[t];
    __syncthreads();
    if (t < 32) {                       // t_vals: (b,r)
        int b = t >> 4, r = t & 15;
        float d = se_b[r];
        for (int c = 0; c < 128; ++c) d += pl[b * 128 + c] * se_w[r * 128 + c];
        float s = sg_[r] * rsqrtf(sv_[r] + 1e-5f);
        float xb = d * s + (sb_[r] - sm_[r] * s);
        tl[t] = 0.5f * xb * (1.f + erff(xb * 0.70710678118654752f));   // exact gelu
    }
    if (t >= 32 && t < 48) {            // softmax rows of phi
        int r = t - 32;
        float m = -1e30f;
        for (int c = 0; c < 128; ++c) m = fmaxf(m, phi[r * 128 + c]);
        float ssum = 0.f;
        for (int c = 0; c < 128; ++c) { float e = expf(phi[r * 128 + c] - m); sp[r][c] = e; ssum += e; }
        float inv = 1.f / ssum;
        for (int c = 0; c < 128; ++c) sp[r][c] *= inv;
    }
    __syncthreads();
    {
        int b = t >> 7, co = t & 127;
        float a = 0.f;
        #pragma unroll
        for (int r = 0; r < 16; ++r) a += tl[b * 16 + r] * sp[r][co];
        dw[t] = 1.f / (1.f + expf(-a));
    }
}

// ---------------- K4: gate * out_pre + BN(1x1 conv identity), relu, f32 NCHW ----------------
__global__ __launch_bounds__(256) void k_final(const bf16* __restrict__ xT,
        const bf16* __restrict__ out_pre, const float* __restrict__ dws2,
        const float* __restrict__ dsT, const float* __restrict__ dw,
        float* __restrict__ out) {
    __shared__ float xtile[64 * 68];     // 64 px x 64 ci, row pad to 68
    __shared__ float otile[64 * 129];    // 64 px x 128 co, row pad to 129
    __shared__ float dwl[128], dsTl[128];
    int g = blockIdx.x;                  // 2048 blocks: b = g>>10, 64 pixels each
    int b = g >> 10;
    int pixbase = (g & 1023) << 6;
    int t = threadIdx.x;
    const bf16* xp = xT + ((size_t)b * HHW + pixbase) * 64;
    for (int i = t; i < 4096; i += 256)
        xtile[(i >> 6) * 68 + (i & 63)] = b2f(xp[i]);
    if (t < 128) { dwl[t] = dw[b * 128 + t]; dsTl[t] = dsT[t]; }
    __syncthreads();
    int co = t >> 1, half = t & 1;
    float4 wr[16];                       // 64 weights in regs (static-indexed)
    const float4* wp = (const float4*)(dws2 + co * 64);
    #pragma unroll
    for (int i = 0; i < 16; ++i) wr[i] = wp[i];
    float dwv = dwl[co], dst = dsTl[co];
    const bf16* opp = out_pre + ((size_t)b * HHW + pixbase) * 128 + co;
    for (int p0 = 0; p0 < 32; ++p0) {
        int p = half * 32 + p0;
        const float* xr = xtile + p * 68;
        float a = 0.f;
        #pragma unroll
        for (int i = 0; i < 16; ++i) {
            float4 xv = *(const float4*)(xr + i * 4);
            a += xv.x * wr[i].x + xv.y * wr[i].y + xv.z * wr[i].z + xv.w * wr[i].w;
        }
        float opre = b2f(opp[(size_t)p * 128]);
        float v = opre * dwv + a + dst;
        otile[p * 129 + co] = fmaxf(v, 0.f);
    }
    __syncthreads();
    float* ob = out + (size_t)b * 128 * HHW + pixbase;
    for (int i = t; i < 8192; i += 256) {
        int cco = i >> 6, pp = i & 63;
        ob[(size_t)cco * HHW + pp] = otile[pp * 129 + cco];
    }
}

extern "C" void kernel_launch(void* const* d_in, const int* in_sizes, int n_in,
                              void* d_out, int out_size, void* d_ws, size_t ws_size,
                              hipStream_t stream) {
    const float* x     = (const float*)d_in[0];
    const float* w_off = (const float*)d_in[1];
    const float* b_off = (const float*)d_in[2];
    const float* w_def = (const float*)d_in[3];
    const float* b_def = (const float*)d_in[4];
    const float* bng   = (const float*)d_in[5];
    const float* bnb   = (const float*)d_in[6];
    const float* bnm   = (const float*)d_in[7];
    const float* bnv   = (const float*)d_in[8];
    const float* se_w  = (const float*)d_in[9];
    const float* se_b  = (const float*)d_in[10];
    const float* sbg   = (const float*)d_in[11];
    const float* sbb   = (const float*)d_in[12];
    const float* sbm   = (const float*)d_in[13];
    const float* sbv   = (const float*)d_in[14];
    const float* phi   = (const float*)d_in[15];
    const float* ds_w  = (const float*)d_in[16];
    const float* dsg   = (const float*)d_in[17];
    const float* dsb   = (const float*)d_in[18];
    const float* dsm   = (const float*)d_in[19];
    const float* dsv   = (const float*)d_in[20];
    float* out = (float*)d_out;          // reference output is float32

    char* w = (char*)d_ws;
    bf16*  xT     = (bf16*)w;   w += 16777216;   // (B,HW,64) bf16
    bf16*  Wf     = (bf16*)w;   w += 147456;     // MFMA-fragment-ordered weights, bf16
    float* wloff  = (float*)w;  w += 46080;      // (576,20) f32
    float* dws2   = (float*)w;  w += 32768;      // (128,64) f32
    float* bnS    = (float*)w;  w += 512;
    float* bnT2   = (float*)w;  w += 512;
    float* dsT    = (float*)w;  w += 512;
    bf16*  opre   = (bf16*)w;   w += 33554432;   // (B,HW,128) bf16
    float* part   = (float*)w;  w += 1048576;    // (256,1024) f32
    float* pooled = (float*)w;  w += 1024;
    float* dwv    = (float*)w;  w += 1024;
    uint4*  orec  = (uint4*)w;  w += 18874368;   // (B*1024 tiles, 576 recs) x 16B corner offsets
    float4* wrec  = (float4*)w; w += 18874368;   // matching bilinear weights (mask-folded)

    hipLaunchKernelGGL(k_prep, dim3(2080), dim3(256), 0, stream, x, xT, w_off, w_def, b_def,
                       bng, bnb, bnm, bnv, ds_w, dsg, dsb, dsm, dsv,
                       Wf, wloff, dws2, bnS, bnT2, dsT);
    hipLaunchKernelGGL(k_off, dim3(512), dim3(256), 0, stream, x, wloff, b_off, orec, wrec);
    hipLaunchKernelGGL(k_deform, dim3(2048), dim3(256), 0, stream, xT, orec, wrec, Wf, bnS, bnT2, opre, part);
    hipLaunchKernelGGL(k_pool, dim3(256), dim3(256), 0, stream, part, pooled);
    hipLaunchKernelGGL(k_se, dim3(1), dim3(256), 0, stream, pooled, se_w, se_b, sbg, sbb, sbm, sbv, phi, dwv);
    hipLaunchKernelGGL(k_final, dim3(2048), dim3(256), 0, stream, xT, opre, dws2, dsT, dwv, out);
}

// Round 10
// 422.504 us; speedup vs baseline: 1.7836x; 1.0479x over previous
//
#include <hip/hip_runtime.h>
#include <hip/hip_bf16.h>

typedef __hip_bfloat16 bf16;
typedef unsigned int u32;
typedef __attribute__((ext_vector_type(8))) short bf16x8;  // 8 bf16 = 4 VGPRs (MFMA A/B frag)
typedef __attribute__((ext_vector_type(4))) float f32x4;   // MFMA C/D frag

#define HHW 65536
#define SBH 584            // S row stride in bf16 (292 dw ≡ 4 mod 32 -> 2-way max on b128 reads = free)
#define SWU 292            // S row stride in u32
#define REDW 132           // staging row stride in f32

__device__ __forceinline__ float b2f(bf16 v) { return __bfloat162float(v); }
__device__ __forceinline__ bf16  f2b(float v) { return __float2bfloat16(v); }
__device__ __forceinline__ float blo(u32 p) { return __uint_as_float(p << 16); }
__device__ __forceinline__ float bhi(u32 p) { return __uint_as_float(p & 0xffff0000u); }
__device__ __forceinline__ u32 pack2(float lo, float hi) {
    bf16 a = f2b(lo), c = f2b(hi);
    unsigned short ua, uc;
    __builtin_memcpy(&ua, &a, 2); __builtin_memcpy(&uc, &c, 2);
    return (u32)ua | ((u32)uc << 16);
}

// ---------------- K0: x transpose (blocks 0..2047) + weight/const prep (blocks 2048..2079) ----------------
__global__ __launch_bounds__(256) void k_prep(const float* __restrict__ x, bf16* __restrict__ xT,
        const float* __restrict__ w_off, const float* __restrict__ w_def, const float* __restrict__ b_def,
        const float* __restrict__ bng, const float* __restrict__ bnb, const float* __restrict__ bnm, const float* __restrict__ bnv,
        const float* __restrict__ ds_w, const float* __restrict__ dsg, const float* __restrict__ dsb,
        const float* __restrict__ dsm, const float* __restrict__ dsv,
        bf16* __restrict__ Wf, float* __restrict__ wloff, float* __restrict__ dws2,
        float* __restrict__ bnS, float* __restrict__ bnT2, float* __restrict__ dsT) {
    __shared__ bf16 tile[64][66];        // u32 row stride 33 (33%32==1 -> conflict-free u32 reads)
    int g = blockIdx.x;
    int t = threadIdx.x;
    if (g < 2048) {                      // transpose x (B,64,H,W) f32 -> xT (B,HW,64) bf16
        int b = g >> 10;
        int pixbase = (g & 1023) << 6;
        int pix = t & 63, ci0 = t >> 6;
        const float* xb = x + ((size_t)b * 64) * HHW + pixbase + pix;
        for (int ci = ci0; ci < 64; ci += 4)
            tile[pix][ci] = f2b(xb[(size_t)ci * HHW]);
        __syncthreads();
        u32* dst32 = (u32*)(xT + ((size_t)b * HHW + pixbase) * 64);
        const u32* t32 = (const u32*)&tile[0][0];
        for (int i = t; i < 2048; i += 256) {      // vectorized u32 (2xbf16) stores
            int pix2 = i >> 5, j = i & 31;
            dst32[i] = t32[pix2 * 33 + j];
        }
        return;
    }
    int tid = (g - 2048) * 256 + t;      // 8192 threads
    // Wf[ct][ks][lane][j]: B-frag order; K = ks*32+(lane>>4)*8+j maps to (ci=K&63, kk=K>>6)
    // matching S's K-major column order k*64+ci.
    for (int i = tid; i < 8 * 18 * 64 * 8; i += 8192) {
        int j = i & 7, lane = (i >> 3) & 63;
        int rem = i >> 9;                // ct*18 + ks
        int ks = rem % 18, ct = rem / 18;
        int co = ct * 16 + (lane & 15);
        int K  = ks * 32 + ((lane >> 4) << 3) + j;
        int ci = K & 63, kk = K >> 6;
        Wf[i] = f2b(w_def[co * 576 + ci * 9 + kk]);
    }
    // wloff[kci][20] = w_off[j][kci] padded with zeros (j<18)
    for (int i = tid; i < 576 * 20; i += 8192) {
        int kci = i / 20, j = i - kci * 20;
        wloff[i] = (j < 18) ? w_off[j * 576 + kci] : 0.f;
    }
    if (tid < 8192) {
        int co = tid >> 6;
        float s2 = dsg[co] * rsqrtf(dsv[co] + 1e-5f);
        dws2[tid] = ds_w[tid] * s2;      // fold ds-BN scale into 1x1 weights
    }
    if (tid < 128) {
        float s = bng[tid] * rsqrtf(bnv[tid] + 1e-5f);
        bnS[tid] = s;
        bnT2[tid] = (b_def[tid] - bnm[tid]) * s + bnb[tid];
        float s2 = dsg[tid] * rsqrtf(dsv[tid] + 1e-5f);
        dsT[tid] = dsb[tid] - dsm[tid] * s2;
    }
}

// ---------------- K1: offset conv 3x3 -> per-(pix,tap) packed sample records ----------------
// rec r = k*64 + pix within tile: crec = 4 clamped corner coords (u8x4),
// wrec = 4 mask-folded bilinear weights (bf16x4 in uint2)
__global__ __launch_bounds__(256) void k_off(const float* __restrict__ x,
        const float* __restrict__ wloff, const float* __restrict__ b_off,
        u32* __restrict__ crec, uint2* __restrict__ wrec) {
    int g = blockIdx.x;               // 512 blocks = b*256 + h
    int b = g >> 8, h = g & 255;
    int t = threadIdx.x;              // w
    float acc[20];
    #pragma unroll
    for (int j = 0; j < 20; ++j) acc[j] = 0.f;
    const float* xb = x + ((size_t)b * 64) * HHW;
    for (int ci = 0; ci < 64; ++ci) {
        const float* xc = xb + (size_t)ci * HHW;
        #pragma unroll
        for (int ky = 0; ky < 3; ++ky) {
            int y = h + ky - 1;
            if ((unsigned)y >= 256u) continue;
            const float* row = xc + y * 256;
            float v0 = (t >= 1)   ? row[t - 1] : 0.f;
            float v1 = row[t];
            float v2 = (t <= 254) ? row[t + 1] : 0.f;
            const float4* wr = (const float4*)(wloff + (ci * 9 + ky * 3) * 20);
            #pragma unroll
            for (int q = 0; q < 5; ++q) {
                float4 wv = wr[q];
                acc[q*4+0] += v0 * wv.x; acc[q*4+1] += v0 * wv.y;
                acc[q*4+2] += v0 * wv.z; acc[q*4+3] += v0 * wv.w;
            }
            #pragma unroll
            for (int q = 0; q < 5; ++q) {
                float4 wv = wr[5 + q];
                acc[q*4+0] += v1 * wv.x; acc[q*4+1] += v1 * wv.y;
                acc[q*4+2] += v1 * wv.z; acc[q*4+3] += v1 * wv.w;
            }
            #pragma unroll
            for (int q = 0; q < 5; ++q) {
                float4 wv = wr[10 + q];
                acc[q*4+0] += v2 * wv.x; acc[q*4+1] += v2 * wv.y;
                acc[q*4+2] += v2 * wv.z; acc[q*4+3] += v2 * wv.w;
            }
        }
    }
    // epilogue: emit 9 packed sample records for this pixel
    int tile = (h << 2) + (t >> 6);
    int pix  = t & 63;
    size_t rbase = ((size_t)(b * 1024 + tile)) * 576;
    #pragma unroll
    for (int k = 0; k < 9; ++k) {
        int ky = k / 3, kx = k - ky * 3;
        float dy = acc[2 * k]     + b_off[2 * k];
        float dx = acc[2 * k + 1] + b_off[2 * k + 1];
        float py = (float)(h + ky - 1) + dy;
        float px = (float)(t + kx - 1) + dx;
        float fy = floorf(py), fx = floorf(px);
        int y0 = (int)fy, x0 = (int)fx;
        float wy1 = py - fy, wx1 = px - fx;
        float wy0 = 1.f - wy1, wx0 = 1.f - wx1;
        int y1 = y0 + 1, x1 = x0 + 1;
        u32 yc0 = (u32)min(max(y0, 0), 255), yc1 = (u32)min(max(y1, 0), 255);
        u32 xc0 = (u32)min(max(x0, 0), 255), xc1 = (u32)min(max(x1, 0), 255);
        float m0 = ((unsigned)y0 < 256u) ? 1.f : 0.f;
        float m1 = ((unsigned)y1 < 256u) ? 1.f : 0.f;
        float n0 = ((unsigned)x0 < 256u) ? 1.f : 0.f;
        float n1 = ((unsigned)x1 < 256u) ? 1.f : 0.f;
        u32 c = yc0 | (xc0 << 8) | (yc1 << 16) | (xc1 << 24);
        uint2 wv;
        wv.x = pack2(wy0 * wx0 * m0 * n0, wy0 * wx1 * m0 * n1);
        wv.y = pack2(wy1 * wx0 * m1 * n0, wy1 * wx1 * m1 * n1);
        crec[rbase + k * 64 + pix] = c;
        wrec[rbase + k * 64 + pix] = wv;
    }
}

// ---------------- K2: deformable conv (MFMA) + BN + pooled partials ----------------
// 512 threads (8 waves), 64-px tile, XCD-swizzled. phase 1: table-driven bilinear
// sampling -> S[64][k*64+ci] bf16; phase 2: 8 waves x (16px x 64co) MFMA
__global__ __launch_bounds__(512, 4) void k_deform(const bf16* __restrict__ xT,
        const u32* __restrict__ crec, const uint2* __restrict__ wrec,
        const bf16* __restrict__ Wf,
        const float* __restrict__ bnS, const float* __restrict__ bnT2,
        bf16* __restrict__ out_pre, float* __restrict__ part) {
    __shared__ bf16 smem[64 * SBH];      // 73 KB -> 2 blocks/CU (16 waves)
    int blk = blockIdx.x;                // 2048; bijective XCD swizzle (2048%8==0)
    int swz = (blk & 7) * 256 + (blk >> 3);
    int b = swz >> 10;
    int tile = swz & 1023;
    int pixbase = tile << 6;
    int t = threadIdx.x;
    int wid = t >> 6, l = t & 63;

    // ---- phase 1: sampling. 16 records per iteration (8 waves x 2 halves) ----
    {
        int cig = l & 31, hf = l >> 5;
        size_t rbase = ((size_t)(b * 1024 + tile)) * 576;
        const u32*  crc = crec + rbase;
        const uint2* wrc = wrec + rbase;
        const u32* xw = (const u32*)xT + (size_t)b * (HHW * 32);
        u32* sw = (u32*)smem;
        int r = (wid << 1) + hf;
        u32  c0 = crc[r];
        uint2 w0 = wrc[r];
        #pragma unroll 6
        for (int it = 0; it < 36; ++it) {
            u32 c = c0; uint2 wv = w0;
            c0 = crc[r + 16]; w0 = wrc[r + 16];   // prefetch (table padded by 1 tile)
            u32 y0 = c & 255u, x0 = (c >> 8) & 255u, y1 = (c >> 16) & 255u, x1 = c >> 24;
            u32 o00 = (y0 << 13) + (x0 << 5) + cig;
            u32 o01 = (y0 << 13) + (x1 << 5) + cig;
            u32 o10 = (y1 << 13) + (x0 << 5) + cig;
            u32 o11 = (y1 << 13) + (x1 << 5) + cig;
            u32 p00 = xw[o00], p01 = xw[o01], p10 = xw[o10], p11 = xw[o11];
            float w00 = blo(wv.x), w01 = bhi(wv.x), w10 = blo(wv.y), w11 = bhi(wv.y);
            float lo = blo(p00)*w00 + blo(p01)*w01 + blo(p10)*w10 + blo(p11)*w11;
            float hi = bhi(p00)*w00 + bhi(p01)*w01 + bhi(p10)*w10 + bhi(p11)*w11;
            int k9 = r >> 6, pix = r & 63;
            sw[pix * SWU + (k9 << 5) + cig] = pack2(lo, hi);
            r += 16;
        }
    }
    __syncthreads();

    // ---- phase 2: MFMA. wave: px group (wid>>1)*16, co half (wid&1)*64 ----
    int pxg = wid >> 1, coh = wid & 1;
    int wp = pxg << 4;
    int lr = l & 15, lg = l >> 4;
    f32x4 acc[4];
    #pragma unroll
    for (int ct = 0; ct < 4; ++ct) acc[ct] = (f32x4){0.f, 0.f, 0.f, 0.f};
    const bf16* arow = smem + (wp + lr) * SBH + lg * 8;
    const bf16* wbase = Wf + l * 8;
    #pragma unroll
    for (int ks = 0; ks < 18; ++ks) {
        bf16x8 af = *(const bf16x8*)(arow + ks * 32);
        #pragma unroll
        for (int ct = 0; ct < 4; ++ct) {
            int cti = coh * 4 + ct;
            bf16x8 bfr = *(const bf16x8*)(wbase + (cti * 18 + ks) * 512);
            acc[ct] = __builtin_amdgcn_mfma_f32_16x16x32_bf16(af, bfr, acc[ct], 0, 0, 0);
        }
    }
    __syncthreads();                     // all waves done reading S before staging reuse
    // ---- epilogue: BN, stage to LDS, coalesced stores + pooled partials ----
    float* red = (float*)smem;           // [64][REDW] f32
    #pragma unroll
    for (int ct = 0; ct < 4; ++ct) {
        int co = (coh * 4 + ct) * 16 + lr;
        float sc = bnS[co], sh = bnT2[co];
        #pragma unroll
        for (int r = 0; r < 4; ++r) {
            int m = lg * 4 + r;
            red[(wp + m) * REDW + co] = acc[ct][r] * sc + sh;
        }
    }
    __syncthreads();
    bf16* op = out_pre + ((size_t)b * HHW + pixbase) * 128;
    for (int i = t; i < 8192; i += 512)
        op[i] = f2b(red[(i >> 7) * REDW + (i & 127)]);
    if (t < 128) {
        float sum = 0.f;
        #pragma unroll
        for (int p = 0; p < 64; ++p) sum += red[p * REDW + t];
        part[((size_t)(b * 128 + t)) * 1024 + tile] = sum;
    }
}

// ---------------- K3a: reduce pooled partials ----------------
__global__ __launch_bounds__(256) void k_pool(const float* __restrict__ part, float* __restrict__ pooled) {
    int bco = blockIdx.x;   // 256 blocks
    int t = threadIdx.x;
    const float* p = part + (size_t)bco * 1024;
    float sum = 0.f;
    for (int i = t; i < 1024; i += 256) sum += p[i];
    __shared__ float r[256];
    r[t] = sum; __syncthreads();
    for (int ofs = 128; ofs > 0; ofs >>= 1) {
        if (t < ofs) r[t] += r[t + ofs];
        __syncthreads();
    }
    if (t == 0) pooled[bco] = r[0] * (1.f / 65536.f);
}

// ---------------- K3b: SE gate (1 block) ----------------
__global__ __launch_bounds__(256) void k_se(const float* __restrict__ pooled,
        const float* __restrict__ se_w, const float* __restrict__ se_b,
        const float* __restrict__ sg_, const float* __restrict__ sb_,
        const float* __restrict__ sm_, const float* __restrict__ sv_,
        const float* __restrict__ phi, float* __restrict__ dw) {
    __shared__ float tl[32];
    __shared__ float sp[16][128];
    __shared__ float pl[256];
    int t = threadIdx.x;
    pl[t] = pooled[t];
    __syncthreads();
    if (t < 32) {                       // t_vals: (b,r)
        int b = t >> 4, r = t & 15;
        float d = se_b[r];
        for (int c = 0; c < 128; ++c) d += pl[b * 128 + c] * se_w[r * 128 + c];
        float s = sg_[r] * rsqrtf(sv_[r] + 1e-5f);
        float xb = d * s + (sb_[r] - sm_[r] * s);
        tl[t] = 0.5f * xb * (1.f + erff(xb * 0.70710678118654752f));   // exact gelu
    }
    if (t >= 32 && t < 48) {            // softmax rows of phi
        int r = t - 32;
        float m = -1e30f;
        for (int c = 0; c < 128; ++c) m = fmaxf(m, phi[r * 128 + c]);
        float ssum = 0.f;
        for (int c = 0; c < 128; ++c) { float e = expf(phi[r * 128 + c] - m); sp[r][c] = e; ssum += e; }
        float inv = 1.f / ssum;
        for (int c = 0; c < 128; ++c) sp[r][c] *= inv;
    }
    __syncthreads();
    {
        int b = t >> 7, co = t & 127;
        float a = 0.f;
        #pragma unroll
        for (int r = 0; r < 16; ++r) a += tl[b * 16 + r] * sp[r][co];
        dw[t] = 1.f / (1.f + expf(-a));
    }
}

// ---------------- K4: gate * out_pre + BN(1x1 conv identity), relu, f32 NCHW ----------------
__global__ __launch_bounds__(256) void k_final(const bf16* __restrict__ xT,
        const bf16* __restrict__ out_pre, const float* __restrict__ dws2,
        const float* __restrict__ dsT, const float* __restrict__ dw,
        float* __restrict__ out) {
    __shared__ float xtile[64 * 68];     // 64 px x 64 ci, row pad to 68
    __shared__ float otile[64 * 129];    // 64 px x 128 co, row pad to 129
    __shared__ float dwl[128], dsTl[128];
    int g = blockIdx.x;                  // 2048 blocks: b = g>>10, 64 pixels each
    int b = g >> 10;
    int pixbase = (g & 1023) << 6;
    int t = threadIdx.x;
    const bf16* xp = xT + ((size_t)b * HHW + pixbase) * 64;
    for (int i = t; i < 4096; i += 256)
        xtile[(i >> 6) * 68 + (i & 63)] = b2f(xp[i]);
    if (t < 128) { dwl[t] = dw[b * 128 + t]; dsTl[t] = dsT[t]; }
    __syncthreads();
    int co = t >> 1, half = t & 1;
    float4 wr[16];                       // 64 weights in regs (static-indexed)
    const float4* wp = (const float4*)(dws2 + co * 64);
    #pragma unroll
    for (int i = 0; i < 16; ++i) wr[i] = wp[i];
    float dwv = dwl[co], dst = dsTl[co];
    const bf16* opp = out_pre + ((size_t)b * HHW + pixbase) * 128 + co;
    for (int p0 = 0; p0 < 32; ++p0) {
        int p = half * 32 + p0;
        const float* xr = xtile + p * 68;
        float a = 0.f;
        #pragma unroll
        for (int i = 0; i < 16; ++i) {
            float4 xv = *(const float4*)(xr + i * 4);
            a += xv.x * wr[i].x + xv.y * wr[i].y + xv.z * wr[i].z + xv.w * wr[i].w;
        }
        float opre = b2f(opp[(size_t)p * 128]);
        float v = opre * dwv + a + dst;
        otile[p * 129 + co] = fmaxf(v, 0.f);
    }
    __syncthreads();
    float* ob = out + (size_t)b * 128 * HHW + pixbase;
    for (int i = t; i < 8192; i += 256) {
        int cco = i >> 6, pp = i & 63;
        ob[(size_t)cco * HHW + pp] = otile[pp * 129 + cco];
    }
}

extern "C" void kernel_launch(void* const* d_in, const int* in_sizes, int n_in,
                              void* d_out, int out_size, void* d_ws, size_t ws_size,
                              hipStream_t stream) {
    const float* x     = (const float*)d_in[0];
    const float* w_off = (const float*)d_in[1];
    const float* b_off = (const float*)d_in[2];
    const float* w_def = (const float*)d_in[3];
    const float* b_def = (const float*)d_in[4];
    const float* bng   = (const float*)d_in[5];
    const float* bnb   = (const float*)d_in[6];
    const float* bnm   = (const float*)d_in[7];
    const float* bnv   = (const float*)d_in[8];
    const float* se_w  = (const float*)d_in[9];
    const float* se_b  = (const float*)d_in[10];
    const float* sbg   = (const float*)d_in[11];
    const float* sbb   = (const float*)d_in[12];
    const float* sbm   = (const float*)d_in[13];
    const float* sbv   = (const float*)d_in[14];
    const float* phi   = (const float*)d_in[15];
    const float* ds_w  = (const float*)d_in[16];
    const float* dsg   = (const float*)d_in[17];
    const float* dsb   = (const float*)d_in[18];
    const float* dsm   = (const float*)d_in[19];
    const float* dsv   = (const float*)d_in[20];
    float* out = (float*)d_out;          // reference output is float32

    char* w = (char*)d_ws;
    bf16*  xT     = (bf16*)w;   w += 16777216;   // (B,HW,64) bf16
    bf16*  Wf     = (bf16*)w;   w += 147456;     // MFMA-fragment-ordered weights, bf16
    float* wloff  = (float*)w;  w += 46080;      // (576,20) f32
    float* dws2   = (float*)w;  w += 32768;      // (128,64) f32
    float* bnS    = (float*)w;  w += 512;
    float* bnT2   = (float*)w;  w += 512;
    float* dsT    = (float*)w;  w += 512;
    bf16*  opre   = (bf16*)w;   w += 33554432;   // (B,HW,128) bf16
    float* part   = (float*)w;  w += 1048576;    // (256,1024) f32
    float* pooled = (float*)w;  w += 1024;
    float* dwv    = (float*)w;  w += 1024;
    u32*   crec   = (u32*)w;    w += 4720896;    // packed corners u8x4 (+1 tile pad)
    uint2* wrec   = (uint2*)w;  w += 9441792;    // packed bilinear weights bf16x4 (+pad)

    hipLaunchKernelGGL(k_prep, dim3(2080), dim3(256), 0, stream, x, xT, w_off, w_def, b_def,
                       bng, bnb, bnm, bnv, ds_w, dsg, dsb, dsm, dsv,
                       Wf, wloff, dws2, bnS, bnT2, dsT);
    hipLaunchKernelGGL(k_off, dim3(512), dim3(256), 0, stream, x, wloff, b_off, crec, wrec);
    hipLaunchKernelGGL(k_deform, dim3(2048), dim3(512), 0, stream, xT, crec, wrec, Wf, bnS, bnT2, opre, part);
    hipLaunchKernelGGL(k_pool, dim3(256), dim3(256), 0, stream, part, pooled);
    hipLaunchKernelGGL(k_se, dim3(1), dim3(256), 0, stream, pooled, se_w, se_b, sbg, sbb, sbm, sbv, phi, dwv);
    hipLaunchKernelGGL(k_final, dim3(2048), dim3(256), 0, stream, xT, opre, dws2, dsT, dwv, out);
}

// Round 11
// 360.595 us; speedup vs baseline: 2.0899x; 1.1717x over previous
//
#include <hip/hip_runtime.h>
#include <hip/hip_bf16.h>

typedef __hip_bfloat16 bf16;
typedef unsigned int u32;
typedef __attribute__((ext_vector_type(8))) short bf16x8;  // 8 bf16 = 4 VGPRs (MFMA A/B frag)
typedef __attribute__((ext_vector_type(4))) float f32x4;   // MFMA C/D frag

#define HHW 65536
#define SBH 584            // S row stride in bf16 (292 dw ≡ 4 mod 32 -> 2-way max on b128 reads = free)
#define SWU 292            // S row stride in u32
#define REDW 132           // staging row stride in f32
#define SOFF_W 20          // offs_lds row stride (f32)

__device__ __forceinline__ float b2f(bf16 v) { return __bfloat162float(v); }
__device__ __forceinline__ bf16  f2b(float v) { return __float2bfloat16(v); }
__device__ __forceinline__ float blo(u32 p) { return __uint_as_float(p << 16); }
__device__ __forceinline__ float bhi(u32 p) { return __uint_as_float(p & 0xffff0000u); }
__device__ __forceinline__ u32 pack2(float lo, float hi) {
    bf16 a = f2b(lo), c = f2b(hi);
    unsigned short ua, uc;
    __builtin_memcpy(&ua, &a, 2); __builtin_memcpy(&uc, &c, 2);
    return (u32)ua | ((u32)uc << 16);
}

// ---------------- K0: x transpose (blocks 0..2047) + weight/const prep (blocks 2048..2079) ----------------
__global__ __launch_bounds__(256) void k_prep(const float* __restrict__ x, bf16* __restrict__ xT,
        const float* __restrict__ w_off, const float* __restrict__ w_def, const float* __restrict__ b_def,
        const float* __restrict__ bng, const float* __restrict__ bnb, const float* __restrict__ bnm, const float* __restrict__ bnv,
        const float* __restrict__ ds_w, const float* __restrict__ dsg, const float* __restrict__ dsb,
        const float* __restrict__ dsm, const float* __restrict__ dsv,
        bf16* __restrict__ Wf, bf16* __restrict__ Woff_f, float* __restrict__ dws2,
        float* __restrict__ bnS, float* __restrict__ bnT2, float* __restrict__ dsT) {
    __shared__ bf16 tile[64][66];        // u32 row stride 33 (33%32==1 -> conflict-free u32 reads)
    int g = blockIdx.x;
    int t = threadIdx.x;
    if (g < 2048) {                      // transpose x (B,64,H,W) f32 -> xT (B,HW,64) bf16
        int b = g >> 10;
        int pixbase = (g & 1023) << 6;
        int pix = t & 63, ci0 = t >> 6;
        const float* xb = x + ((size_t)b * 64) * HHW + pixbase + pix;
        for (int ci = ci0; ci < 64; ci += 4)
            tile[pix][ci] = f2b(xb[(size_t)ci * HHW]);
        __syncthreads();
        u32* dst32 = (u32*)(xT + ((size_t)b * HHW + pixbase) * 64);
        const u32* t32 = (const u32*)&tile[0][0];
        for (int i = t; i < 2048; i += 256) {      // vectorized u32 (2xbf16) stores
            int pix2 = i >> 5, j = i & 31;
            dst32[i] = t32[pix2 * 33 + j];
        }
        return;
    }
    int tid = (g - 2048) * 256 + t;      // 8192 threads
    // Wf[ct][ks][lane][j]: B-frag order; K = ks*32+(lane>>4)*8+j maps to (ci=K&63, kk=K>>6)
    // matching S's K-major column order k*64+ci.
    for (int i = tid; i < 8 * 18 * 64 * 8; i += 8192) {
        int j = i & 7, lane = (i >> 3) & 63;
        int rem = i >> 9;                // ct*18 + ks
        int ks = rem % 18, ct = rem / 18;
        int co = ct * 16 + (lane & 15);
        int K  = ks * 32 + ((lane >> 4) << 3) + j;
        int ci = K & 63, kk = K >> 6;
        Wf[i] = f2b(w_def[co * 576 + ci * 9 + kk]);
    }
    // Woff_f: same fragment order for the offset conv (18 couts zero-padded to 32, 2 co-tiles)
    for (int i = tid; i < 2 * 18 * 64 * 8; i += 8192) {
        int j = i & 7, lane = (i >> 3) & 63;
        int rem = i >> 9;                // ct*18 + ks
        int ks = rem % 18, ct = rem / 18;
        int co = ct * 16 + (lane & 15);
        int K  = ks * 32 + ((lane >> 4) << 3) + j;
        int ci = K & 63, kk = K >> 6;
        Woff_f[i] = (co < 18) ? f2b(w_off[co * 576 + ci * 9 + kk]) : f2b(0.f);
    }
    if (tid < 8192) {
        int co = tid >> 6;
        float s2 = dsg[co] * rsqrtf(dsv[co] + 1e-5f);
        dws2[tid] = ds_w[tid] * s2;      // fold ds-BN scale into 1x1 weights
    }
    if (tid < 128) {
        float s = bng[tid] * rsqrtf(bnv[tid] + 1e-5f);
        bnS[tid] = s;
        bnT2[tid] = (b_def[tid] - bnm[tid]) * s + bnb[tid];
        float s2 = dsg[tid] * rsqrtf(dsv[tid] + 1e-5f);
        dsT[tid] = dsb[tid] - dsm[tid] * s2;
    }
}

// ---------------- K2: FUSED offset-conv (MFMA) + records + deformable conv (MFMA) + BN + pool ----------------
// 512 threads (8 waves), 64-px tile, XCD-swizzled.
// 0a: offset conv via MFMA, A-frags loaded directly from xT (edge-predicated) -> offs in LDS
// 0b: per-(pix,tap) bilinear records computed into LDS
// 1:  table-driven gather -> S[64][k*64+ci] bf16 in LDS
// 2:  8 waves x (16px x 64co) deform MFMA; epilogue BN + stores + pooled partials
__global__ __launch_bounds__(512, 4) void k_deform(const bf16* __restrict__ xT,
        const bf16* __restrict__ Woff_f, const float* __restrict__ b_off,
        const bf16* __restrict__ Wf,
        const float* __restrict__ bnS, const float* __restrict__ bnT2,
        bf16* __restrict__ out_pre, float* __restrict__ part) {
    __shared__ bf16 smem[64 * SBH + 2304 + 1152];   // S (73KB) | wrec (4.5KB) | crec (2.25KB) = 79.75KB
    uint2* wrl = (uint2*)(smem + 64 * SBH);
    u32*   crl = (u32*)(smem + 64 * SBH + 2304);
    int blk = blockIdx.x;                // 2048; bijective XCD swizzle (2048%8==0)
    int swz = (blk & 7) * 256 + (blk >> 3);
    int b = swz >> 10;
    int tile = swz & 1023;
    int pixbase = tile << 6;
    int h = pixbase >> 8;
    int w0 = pixbase & 255;
    int t = threadIdx.x;
    int wid = t >> 6, l = t & 63;
    int lr = l & 15, lg = l >> 4;

    // ---- phase 0a: offset conv. wave: px group (wid&3)*16, co-tile (wid>>2) ----
    {
        int pxg0 = wid & 3, ct0 = wid >> 2;
        int pix = pxg0 * 16 + lr;        // A row = lane&15
        const bf16* xb = xT + (size_t)b * HHW * 64;
        f32x4 oacc = (f32x4){0.f, 0.f, 0.f, 0.f};
        #pragma unroll
        for (int ks = 0; ks < 18; ++ks) {
            int K0 = ks * 32 + lg * 8;
            int k9 = K0 >> 6, ci0 = K0 & 63;
            int ky = k9 / 3, kx = k9 - 3 * ky;
            int py = h + ky - 1;
            int px = w0 + pix + kx - 1;
            bf16x8 af = {0, 0, 0, 0, 0, 0, 0, 0};
            if ((unsigned)py < 256u && (unsigned)px < 256u)
                af = *(const bf16x8*)(xb + ((size_t)(py * 256 + px)) * 64 + ci0);
            bf16x8 bfr = *(const bf16x8*)(Woff_f + ((ct0 * 18 + ks) * 64 + l) * 8);
            oacc = __builtin_amdgcn_mfma_f32_16x16x32_bf16(af, bfr, oacc, 0, 0, 0);
        }
        float* offs_lds = (float*)smem;  // [64][SOFF_W], aliases S (dead until phase 1)
        int co = ct0 * 16 + lr;          // D col = lane&15
        if (co < 18) {
            float bo = b_off[co];
            #pragma unroll
            for (int r = 0; r < 4; ++r) {
                int m = pxg0 * 16 + lg * 4 + r;   // D row = (lane>>4)*4+r
                offs_lds[m * SOFF_W + co] = oacc[r] + bo;
            }
        }
    }
    __syncthreads();

    // ---- phase 0b: bilinear sample records into LDS ----
    {
        const float* offs_lds = (const float*)smem;
        for (int r = t; r < 576; r += 512) {
            int pix = r & 63, k = r >> 6;
            int ky = k / 3, kx = k - 3 * ky;
            float dy = offs_lds[pix * SOFF_W + 2 * k];
            float dx = offs_lds[pix * SOFF_W + 2 * k + 1];
            float py = (float)(h + ky - 1) + dy;
            float px = (float)(w0 + pix + kx - 1) + dx;
            float fy = floorf(py), fx = floorf(px);
            int y0 = (int)fy, x0 = (int)fx;
            float wy1 = py - fy, wx1 = px - fx;
            float wy0 = 1.f - wy1, wx0 = 1.f - wx1;
            int y1 = y0 + 1, x1 = x0 + 1;
            u32 yc0 = (u32)min(max(y0, 0), 255), yc1 = (u32)min(max(y1, 0), 255);
            u32 xc0 = (u32)min(max(x0, 0), 255), xc1 = (u32)min(max(x1, 0), 255);
            float m0 = ((unsigned)y0 < 256u) ? 1.f : 0.f;
            float m1 = ((unsigned)y1 < 256u) ? 1.f : 0.f;
            float n0 = ((unsigned)x0 < 256u) ? 1.f : 0.f;
            float n1 = ((unsigned)x1 < 256u) ? 1.f : 0.f;
            crl[r] = yc0 | (xc0 << 8) | (yc1 << 16) | (xc1 << 24);
            uint2 wv;
            wv.x = pack2(wy0 * wx0 * m0 * n0, wy0 * wx1 * m0 * n1);
            wv.y = pack2(wy1 * wx0 * m1 * n0, wy1 * wx1 * m1 * n1);
            wrl[r] = wv;
        }
    }
    __syncthreads();

    // ---- phase 1: gather. 16 records per iteration (8 waves x 2 halves) ----
    {
        int cig = l & 31, hf = l >> 5;
        const u32* xw = (const u32*)xT + (size_t)b * (HHW * 32);
        u32* sw = (u32*)smem;
        #pragma unroll 4
        for (int it = 0; it < 36; ++it) {
            int r = it * 16 + (wid << 1) + hf;
            u32 c = crl[r];
            uint2 wv = wrl[r];
            u32 y0 = c & 255u, x0 = (c >> 8) & 255u, y1 = (c >> 16) & 255u, x1 = c >> 24;
            u32 o00 = (y0 << 13) + (x0 << 5) + cig;
            u32 o01 = (y0 << 13) + (x1 << 5) + cig;
            u32 o10 = (y1 << 13) + (x0 << 5) + cig;
            u32 o11 = (y1 << 13) + (x1 << 5) + cig;
            u32 p00 = xw[o00], p01 = xw[o01], p10 = xw[o10], p11 = xw[o11];
            float w00 = blo(wv.x), w01 = bhi(wv.x), w10 = blo(wv.y), w11 = bhi(wv.y);
            float lo = blo(p00)*w00 + blo(p01)*w01 + blo(p10)*w10 + blo(p11)*w11;
            float hi = bhi(p00)*w00 + bhi(p01)*w01 + bhi(p10)*w10 + bhi(p11)*w11;
            int k9 = r >> 6, pix = r & 63;
            sw[pix * SWU + (k9 << 5) + cig] = pack2(lo, hi);
        }
    }
    __syncthreads();

    // ---- phase 2: deform MFMA. wave: px group (wid>>1)*16, co half (wid&1)*64 ----
    int pxg = wid >> 1, coh = wid & 1;
    int wp = pxg << 4;
    f32x4 acc[4];
    #pragma unroll
    for (int ct = 0; ct < 4; ++ct) acc[ct] = (f32x4){0.f, 0.f, 0.f, 0.f};
    const bf16* arow = smem + (wp + lr) * SBH + lg * 8;
    const bf16* wbase = Wf + l * 8;
    #pragma unroll
    for (int ks = 0; ks < 18; ++ks) {
        bf16x8 af = *(const bf16x8*)(arow + ks * 32);
        #pragma unroll
        for (int ct = 0; ct < 4; ++ct) {
            int cti = coh * 4 + ct;
            bf16x8 bfr = *(const bf16x8*)(wbase + (cti * 18 + ks) * 512);
            acc[ct] = __builtin_amdgcn_mfma_f32_16x16x32_bf16(af, bfr, acc[ct], 0, 0, 0);
        }
    }
    __syncthreads();                     // all waves done reading S before staging reuse
    // ---- epilogue: BN, stage to LDS, coalesced stores + pooled partials ----
    float* red = (float*)smem;           // [64][REDW] f32
    #pragma unroll
    for (int ct = 0; ct < 4; ++ct) {
        int co = (coh * 4 + ct) * 16 + lr;
        float sc = bnS[co], sh = bnT2[co];
        #pragma unroll
        for (int r = 0; r < 4; ++r) {
            int m = lg * 4 + r;
            red[(wp + m) * REDW + co] = acc[ct][r] * sc + sh;
        }
    }
    __syncthreads();
    bf16* op = out_pre + ((size_t)b * HHW + pixbase) * 128;
    for (int i = t; i < 8192; i += 512)
        op[i] = f2b(red[(i >> 7) * REDW + (i & 127)]);
    if (t < 128) {
        float sum = 0.f;
        #pragma unroll
        for (int p = 0; p < 64; ++p) sum += red[p * REDW + t];
        part[((size_t)(b * 128 + t)) * 1024 + tile] = sum;
    }
}

// ---------------- K3a: reduce pooled partials ----------------
__global__ __launch_bounds__(256) void k_pool(const float* __restrict__ part, float* __restrict__ pooled) {
    int bco = blockIdx.x;   // 256 blocks
    int t = threadIdx.x;
    const float* p = part + (size_t)bco * 1024;
    float sum = 0.f;
    for (int i = t; i < 1024; i += 256) sum += p[i];
    __shared__ float r[256];
    r[t] = sum; __syncthreads();
    for (int ofs = 128; ofs > 0; ofs >>= 1) {
        if (t < ofs) r[t] += r[t + ofs];
        __syncthreads();
    }
    if (t == 0) pooled[bco] = r[0] * (1.f / 65536.f);
}

// ---------------- K3b: SE gate (1 block) ----------------
__global__ __launch_bounds__(256) void k_se(const float* __restrict__ pooled,
        const float* __restrict__ se_w, const float* __restrict__ se_b,
        const float* __restrict__ sg_, const float* __restrict__ sb_,
        const float* __restrict__ sm_, const float* __restrict__ sv_,
        const float* __restrict__ phi, float* __restrict__ dw) {
    __shared__ float tl[32];
    __shared__ float sp[16][128];
    __shared__ float pl[256];
    int t = threadIdx.x;
    pl[t] = pooled[t];
    __syncthreads();
    if (t < 32) {                       // t_vals: (b,r)
        int b = t >> 4, r = t & 15;
        float d = se_b[r];
        for (int c = 0; c < 128; ++c) d += pl[b * 128 + c] * se_w[r * 128 + c];
        float s = sg_[r] * rsqrtf(sv_[r] + 1e-5f);
        float xb = d * s + (sb_[r] - sm_[r] * s);
        tl[t] = 0.5f * xb * (1.f + erff(xb * 0.70710678118654752f));   // exact gelu
    }
    if (t >= 32 && t < 48) {            // softmax rows of phi
        int r = t - 32;
        float m = -1e30f;
        for (int c = 0; c < 128; ++c) m = fmaxf(m, phi[r * 128 + c]);
        float ssum = 0.f;
        for (int c = 0; c < 128; ++c) { float e = expf(phi[r * 128 + c] - m); sp[r][c] = e; ssum += e; }
        float inv = 1.f / ssum;
        for (int c = 0; c < 128; ++c) sp[r][c] *= inv;
    }
    __syncthreads();
    {
        int b = t >> 7, co = t & 127;
        float a = 0.f;
        #pragma unroll
        for (int r = 0; r < 16; ++r) a += tl[b * 16 + r] * sp[r][co];
        dw[t] = 1.f / (1.f + expf(-a));
    }
}

// ---------------- K4: gate * out_pre + BN(1x1 conv identity), relu, f32 NCHW ----------------
__global__ __launch_bounds__(256) void k_final(const bf16* __restrict__ xT,
        const bf16* __restrict__ out_pre, const float* __restrict__ dws2,
        const float* __restrict__ dsT, const float* __restrict__ dw,
        float* __restrict__ out) {
    __shared__ float xtile[64 * 68];     // 64 px x 64 ci, row pad to 68
    __shared__ float otile[64 * 129];    // 64 px x 128 co, row pad to 129
    __shared__ float dwl[128], dsTl[128];
    int g = blockIdx.x;                  // 2048 blocks: b = g>>10, 64 pixels each
    int b = g >> 10;
    int pixbase = (g & 1023) << 6;
    int t = threadIdx.x;
    const bf16* xp = xT + ((size_t)b * HHW + pixbase) * 64;
    for (int i = t; i < 4096; i += 256)
        xtile[(i >> 6) * 68 + (i & 63)] = b2f(xp[i]);
    if (t < 128) { dwl[t] = dw[b * 128 + t]; dsTl[t] = dsT[t]; }
    __syncthreads();
    int co = t >> 1, half = t & 1;
    float4 wr[16];                       // 64 weights in regs (static-indexed)
    const float4* wp = (const float4*)(dws2 + co * 64);
    #pragma unroll
    for (int i = 0; i < 16; ++i) wr[i] = wp[i];
    float dwv = dwl[co], dst = dsTl[co];
    const bf16* opp = out_pre + ((size_t)b * HHW + pixbase) * 128 + co;
    for (int p0 = 0; p0 < 32; ++p0) {
        int p = half * 32 + p0;
        const float* xr = xtile + p * 68;
        float a = 0.f;
        #pragma unroll
        for (int i = 0; i < 16; ++i) {
            float4 xv = *(const float4*)(xr + i * 4);
            a += xv.x * wr[i].x + xv.y * wr[i].y + xv.z * wr[i].z + xv.w * wr[i].w;
        }
        float opre = b2f(opp[(size_t)p * 128]);
        float v = opre * dwv + a + dst;
        otile[p * 129 + co] = fmaxf(v, 0.f);
    }
    __syncthreads();
    float* ob = out + (size_t)b * 128 * HHW + pixbase;
    for (int i = t; i < 8192; i += 256) {
        int cco = i >> 6, pp = i & 63;
        ob[(size_t)cco * HHW + pp] = otile[pp * 129 + cco];
    }
}

extern "C" void kernel_launch(void* const* d_in, const int* in_sizes, int n_in,
                              void* d_out, int out_size, void* d_ws, size_t ws_size,
                              hipStream_t stream) {
    const float* x     = (const float*)d_in[0];
    const float* w_off = (const float*)d_in[1];
    const float* b_off = (const float*)d_in[2];
    const float* w_def = (const float*)d_in[3];
    const float* b_def = (const float*)d_in[4];
    const float* bng   = (const float*)d_in[5];
    const float* bnb   = (const float*)d_in[6];
    const float* bnm   = (const float*)d_in[7];
    const float* bnv   = (const float*)d_in[8];
    const float* se_w  = (const float*)d_in[9];
    const float* se_b  = (const float*)d_in[10];
    const float* sbg   = (const float*)d_in[11];
    const float* sbb   = (const float*)d_in[12];
    const float* sbm   = (const float*)d_in[13];
    const float* sbv   = (const float*)d_in[14];
    const float* phi   = (const float*)d_in[15];
    const float* ds_w  = (const float*)d_in[16];
    const float* dsg   = (const float*)d_in[17];
    const float* dsb   = (const float*)d_in[18];
    const float* dsm   = (const float*)d_in[19];
    const float* dsv   = (const float*)d_in[20];
    float* out = (float*)d_out;          // reference output is float32

    char* w = (char*)d_ws;
    bf16*  xT     = (bf16*)w;   w += 16777216;   // (B,HW,64) bf16
    bf16*  Wf     = (bf16*)w;   w += 147456;     // deform weights, MFMA fragment order
    bf16*  Woff_f = (bf16*)w;   w += 36864;      // offset-conv weights, fragment order (18->32 pad)
    float* dws2   = (float*)w;  w += 32768;      // (128,64) f32
    float* bnS    = (float*)w;  w += 512;
    float* bnT2   = (float*)w;  w += 512;
    float* dsT    = (float*)w;  w += 512;
    bf16*  opre   = (bf16*)w;   w += 33554432;   // (B,HW,128) bf16
    float* part   = (float*)w;  w += 1048576;    // (256,1024) f32
    float* pooled = (float*)w;  w += 1024;
    float* dwv    = (float*)w;  w += 1024;

    hipLaunchKernelGGL(k_prep, dim3(2080), dim3(256), 0, stream, x, xT, w_off, w_def, b_def,
                       bng, bnb, bnm, bnv, ds_w, dsg, dsb, dsm, dsv,
                       Wf, Woff_f, dws2, bnS, bnT2, dsT);
    hipLaunchKernelGGL(k_deform, dim3(2048), dim3(512), 0, stream, xT, Woff_f, b_off, Wf, bnS, bnT2, opre, part);
    hipLaunchKernelGGL(k_pool, dim3(256), dim3(256), 0, stream, part, pooled);
    hipLaunchKernelGGL(k_se, dim3(1), dim3(256), 0, stream, pooled, se_w, se_b, sbg, sbb, sbm, sbv, phi, dwv);
    hipLaunchKernelGGL(k_final, dim3(2048), dim3(256), 0, stream, xT, opre, dws2, dsT, dwv, out);
}